// Round 1
// baseline (848.261 us; speedup 1.0000x reference)
//
#include <hip/hip_runtime.h>
#include <hip/hip_bf16.h>

#define DIM   256
#define NH    8
#define HE    32
#define ROWS  32768          // B*TS_D*SEG = 16*32*64
#define EPS_LN 1e-3f

typedef float f32x4 __attribute__((ext_vector_type(4)));
typedef short s16x8 __attribute__((ext_vector_type(8)));

__device__ __forceinline__ unsigned short f2bf(float f){
    union { float f; unsigned int u; } v; v.f = f;
    unsigned int u = v.u;
    return (unsigned short)((u + 0x7fffu + ((u >> 16) & 1u)) >> 16);   // RNE
}

__device__ __forceinline__ float gelu_f(float x){
    return 0.5f * x * (1.0f + erff(x * 0.70710678118654752440f));      // exact gelu
}

__device__ __forceinline__ void mfma16(f32x4& acc, s16x8 a, s16x8 b){
    asm volatile("v_mfma_f32_16x16x32_bf16 %0, %1, %2, %0"
                 : "+v"(acc) : "v"(a), "v"(b));
}

// ---------------- weight transpose + bf16 convert: Wt[n*K+k] = W[k*N+n] ----
__global__ void transp_k(const float* __restrict__ W, unsigned short* __restrict__ Wt,
                         int K, int N){
    int idx = blockIdx.x * 256 + threadIdx.x;
    if (idx >= K * N) return;
    int k = idx / N, n = idx % N;
    Wt[(long)n * K + k] = f2bf(W[idx]);
}

// ---------------- GEMM: C[M,N] = act(A[M,K] @ W[K,N] + bias) ----------------
// A fp32 row-major, Wt = bf16 pre-transposed W (N x K row-major).
// 64x64 tile, BK=32, 256 threads = 4 waves in 2x2, each wave 32x32 (2x2 frags).
template<int ACT>
__global__ __launch_bounds__(256) void gemm_k(const float* __restrict__ A,
        const unsigned short* __restrict__ Wt, const float* __restrict__ bias,
        float* __restrict__ C, int M, int N, int K){
    __shared__ __align__(16) unsigned short As[64 * 40];   // pad 32->40 (80B rows, 16B aligned)
    __shared__ __align__(16) unsigned short Bs[64 * 40];
    const int tid  = threadIdx.x;
    const long row0 = (long)blockIdx.x * 64;
    const long col0 = (long)blockIdx.y * 64;
    const int w = tid >> 6, lane = tid & 63;
    const int wm = w >> 1, wn = w & 1;
    const int sm  = tid >> 2;            // staging row 0..63
    const int skq = (tid & 3) << 3;      // staging k-offset 0,8,16,24
    const float*          Ap = A  + (row0 + sm) * K + skq;
    const unsigned short* Bp = Wt + (col0 + sm) * K + skq;
    const int sidx = sm * 40 + skq;
    const int koff = (lane >> 4) << 3;
    const int rA0 = (wm * 32 + (lane & 15)) * 40 + koff;
    const int rB0 = (wn * 32 + (lane & 15)) * 40 + koff;
    f32x4 acc00 = {0,0,0,0}, acc01 = {0,0,0,0}, acc10 = {0,0,0,0}, acc11 = {0,0,0,0};
    for (int k0 = 0; k0 < K; k0 += 32){
        float4 a0 = *reinterpret_cast<const float4*>(Ap + k0);
        float4 a1 = *reinterpret_cast<const float4*>(Ap + k0 + 4);
        s16x8 av;
        av[0]=(short)f2bf(a0.x); av[1]=(short)f2bf(a0.y);
        av[2]=(short)f2bf(a0.z); av[3]=(short)f2bf(a0.w);
        av[4]=(short)f2bf(a1.x); av[5]=(short)f2bf(a1.y);
        av[6]=(short)f2bf(a1.z); av[7]=(short)f2bf(a1.w);
        s16x8 bv = *reinterpret_cast<const s16x8*>(Bp + k0);
        *reinterpret_cast<s16x8*>(&As[sidx]) = av;
        *reinterpret_cast<s16x8*>(&Bs[sidx]) = bv;
        __syncthreads();
        s16x8 af0 = *reinterpret_cast<const s16x8*>(&As[rA0]);
        s16x8 af1 = *reinterpret_cast<const s16x8*>(&As[rA0 + 16 * 40]);
        s16x8 bf0 = *reinterpret_cast<const s16x8*>(&Bs[rB0]);
        s16x8 bf1 = *reinterpret_cast<const s16x8*>(&Bs[rB0 + 16 * 40]);
        mfma16(acc00, af0, bf0);
        mfma16(acc01, af0, bf1);
        mfma16(acc10, af1, bf0);
        mfma16(acc11, af1, bf1);
        __syncthreads();
    }
    const int r0 = (lane >> 4) << 2;   // D row = (lane>>4)*4 + r  (m89-verified)
    const int cb = lane & 15;          // D col = lane&15
    auto wr = [&](const f32x4& a, int m, int n){
        long grow = row0 + wm * 32 + m * 16 + r0;
        int  gcol = (int)col0 + wn * 32 + n * 16 + cb;
        float bb = bias[gcol];
        #pragma unroll
        for (int r = 0; r < 4; r++){
            float v = a[r] + bb;
            if (ACT) v = gelu_f(v);
            C[(grow + r) * N + gcol] = v;
        }
    };
    wr(acc00,0,0); wr(acc01,0,1); wr(acc10,1,0); wr(acc11,1,1);
}

// ---------------- fused attention: one workgroup per (batch j, head h) ------
// QMODE 0: qbase = j*L ; QMODE 1 (router): qbase = (j>>4)*L  (j//16, L=10)
template<int L, int S, int QMODE>
__global__ __launch_bounds__(256) void attn_k(const float* __restrict__ Q,
        const float* __restrict__ Kp, const float* __restrict__ Vp,
        float* __restrict__ O){
    __shared__ float Qs[L][36];
    __shared__ float Ks[S][36];
    __shared__ float Vs[S][36];
    __shared__ float Sc[L][S + 1];
    const int j = blockIdx.x >> 3, h = blockIdx.x & 7;
    const int tid = threadIdx.x;
    const long qbase = QMODE ? (long)(j >> 4) * L : (long)j * L;
    const long kbase = (long)j * S;
    const long obase = (long)j * L;
    const int hoff = h * HE;
    for (int idx = tid; idx < L * 8; idx += 256){
        int i = idx >> 3, e4 = (idx & 7) << 2;
        *reinterpret_cast<float4*>(&Qs[i][e4]) =
            *reinterpret_cast<const float4*>(Q + (qbase + i) * DIM + hoff + e4);
    }
    for (int idx = tid; idx < S * 8; idx += 256){
        int i = idx >> 3, e4 = (idx & 7) << 2;
        *reinterpret_cast<float4*>(&Ks[i][e4]) =
            *reinterpret_cast<const float4*>(Kp + (kbase + i) * DIM + hoff + e4);
        *reinterpret_cast<float4*>(&Vs[i][e4]) =
            *reinterpret_cast<const float4*>(Vp + (kbase + i) * DIM + hoff + e4);
    }
    __syncthreads();
    for (int idx = tid; idx < L * S; idx += 256){
        int i = idx / S, jj = idx % S;
        float d = 0.f;
        #pragma unroll
        for (int q4 = 0; q4 < 8; q4++){
            float4 a = *reinterpret_cast<const float4*>(&Qs[i][q4 * 4]);
            float4 b = *reinterpret_cast<const float4*>(&Ks[jj][q4 * 4]);
            d += a.x * b.x + a.y * b.y + a.z * b.z + a.w * b.w;
        }
        Sc[i][jj] = d * 0.17677669529663687f;   // 1/sqrt(32)
    }
    __syncthreads();
    if (tid < L){
        float mx = -1e30f;
        for (int jj = 0; jj < S; jj++) mx = fmaxf(mx, Sc[tid][jj]);
        float s = 0.f;
        for (int jj = 0; jj < S; jj++){ float e = expf(Sc[tid][jj] - mx); Sc[tid][jj] = e; s += e; }
        float inv = 1.f / s;
        for (int jj = 0; jj < S; jj++) Sc[tid][jj] *= inv;
    }
    __syncthreads();
    for (int idx = tid; idx < L * 8; idx += 256){
        int i = idx >> 3, e4 = (idx & 7) << 2;
        float4 o = {0.f, 0.f, 0.f, 0.f};
        for (int jj = 0; jj < S; jj++){
            float s = Sc[i][jj];
            float4 v = *reinterpret_cast<const float4*>(&Vs[jj][e4]);
            o.x += s * v.x; o.y += s * v.y; o.z += s * v.z; o.w += s * v.w;
        }
        *reinterpret_cast<float4*>(O + (obase + i) * DIM + hoff + e4) = o;
    }
}

// ---------------- LayerNorm of (X + R), optional row permutation on write ---
// PERM 0: rout=row. PERM 1: (b,t,seg)->(b,seg,t).  PERM 2: (b,seg,t)->(b,t,seg).
template<int PERM>
__global__ __launch_bounds__(256) void ln_k(const float* __restrict__ X,
        const float* __restrict__ R, const float* __restrict__ g,
        const float* __restrict__ be, float* __restrict__ Y){
    const int wid = threadIdx.x >> 6, lane = threadIdx.x & 63;
    const long row = (long)blockIdx.x * 4 + wid;
    float4 xv = *reinterpret_cast<const float4*>(X + row * DIM + lane * 4);
    float4 rv = *reinterpret_cast<const float4*>(R + row * DIM + lane * 4);
    float4 v = {xv.x + rv.x, xv.y + rv.y, xv.z + rv.z, xv.w + rv.w};
    float s = v.x + v.y + v.z + v.w;
    #pragma unroll
    for (int m = 1; m < 64; m <<= 1) s += __shfl_xor(s, m, 64);
    float mean = s * (1.f / 256.f);
    float dx = v.x - mean, dy = v.y - mean, dz = v.z - mean, dw = v.w - mean;
    float q = dx * dx + dy * dy + dz * dz + dw * dw;
    #pragma unroll
    for (int m = 1; m < 64; m <<= 1) q += __shfl_xor(q, m, 64);
    float rstd = rsqrtf(q * (1.f / 256.f) + EPS_LN);
    float4 gv = *reinterpret_cast<const float4*>(g  + lane * 4);
    float4 bv = *reinterpret_cast<const float4*>(be + lane * 4);
    long rout = row;
    if (PERM == 1){ int b = (int)(row >> 11), rem = (int)row & 2047, t = rem >> 6, sg = rem & 63;
                    rout = (long)b * 2048 + sg * 32 + t; }
    if (PERM == 2){ int b = (int)(row >> 11), rem = (int)row & 2047, sg = rem >> 5, t = rem & 31;
                    rout = (long)b * 2048 + t * 64 + sg; }
    float4 o = { dx * rstd * gv.x + bv.x, dy * rstd * gv.y + bv.y,
                 dz * rstd * gv.z + bv.z, dw * rstd * gv.w + bv.w };
    *reinterpret_cast<float4*>(Y + rout * DIM + lane * 4) = o;
}

extern "C" void kernel_launch(void* const* d_in, const int* in_sizes, int n_in,
                              void* d_out, int out_size, void* d_ws, size_t ws_size,
                              hipStream_t stream){
    const float* x      = (const float*)d_in[0];
    const float* router = (const float*)d_in[1];
    const float* bia[16]; // biases aligned with weight order below
    const int bsel[16] = {3,5,7,9, 11,13,15,17, 19,21,23,25, 35,37,39,41};
    for (int i = 0; i < 16; i++) bia[i] = (const float*)d_in[bsel[i]];
    const float* n1g = (const float*)d_in[26]; const float* n1b = (const float*)d_in[27];
    const float* n2g = (const float*)d_in[28]; const float* n2b = (const float*)d_in[29];
    const float* n3g = (const float*)d_in[30]; const float* n3b = (const float*)d_in[31];
    const float* n4g = (const float*)d_in[32]; const float* n4b = (const float*)d_in[33];

    char* ws = (char*)d_ws;
    const size_t ACTB = (size_t)ROWS * DIM * 4;            // 33.55 MB
    float* buf0 = (float*)(ws);
    float* buf1 = (float*)(ws + 1 * ACTB);
    float* buf2 = (float*)(ws + 2 * ACTB);
    float* buf3 = (float*)(ws + 3 * ACTB);
    float* buf4 = (float*)(ws + 4 * ACTB);
    float* buf5 = (float*)(ws + 5 * ACTB);
    float* bufH = buf0;                                     // 32768x1024 aliases buf0..buf3
    size_t off = 6 * ACTB;
    float* bufS1 = (float*)(ws + off); off += (size_t)10240 * 256 * 4;
    float* bufS2 = (float*)(ws + off); off += (size_t)10240 * 256 * 4;
    float* bufR  = (float*)(ws + off); off += (size_t)640 * 256 * 4;
    unsigned short* wtbase = (unsigned short*)(ws + off);

    // ---- weight transposes (order: tq tk tv to sq sk sv so rq rk rv ro m1w1 m1w2 m2w1 m2w2)
    const int wsel[16] = {2,4,6,8, 10,12,14,16, 18,20,22,24, 34,36,38,40};
    const int wKs[16]  = {256,256,256,256, 256,256,256,256, 256,256,256,256, 256,1024,256,1024};
    const int wNs[16]  = {256,256,256,256, 256,256,256,256, 256,256,256,256, 1024,256,1024,256};
    unsigned short* wt[16];
    { size_t o = 0;
      for (int i = 0; i < 16; i++){ wt[i] = wtbase + o; o += (size_t)wKs[i] * wNs[i]; } }
    for (int i = 0; i < 16; i++){
        int total = wKs[i] * wNs[i];
        transp_k<<<(total + 255) / 256, 256, 0, stream>>>((const float*)d_in[wsel[i]],
                                                          wt[i], wKs[i], wNs[i]);
    }
    auto G = [&](const float* A, int wi, float* C, int M, int N, int K, bool act){
        dim3 g(M / 64, N / 64);
        if (act) gemm_k<1><<<g, 256, 0, stream>>>(A, wt[wi], bia[wi], C, M, N, K);
        else     gemm_k<0><<<g, 256, 0, stream>>>(A, wt[wi], bia[wi], C, M, N, K);
    };

    // ---------------- stage 1: time attention over SEG within each (b, t) ----
    G(x, 0, buf0, ROWS, 256, 256, false);                 // q1
    G(x, 1, buf1, ROWS, 256, 256, false);                 // k1
    G(x, 2, buf2, ROWS, 256, 256, false);                 // v1
    attn_k<64,64,0><<<dim3(512 * 8), 256, 0, stream>>>(buf0, buf1, buf2, buf3);
    G(buf3, 3, buf5, ROWS, 256, 256, false);              // time_enc (o-proj)
    ln_k<0><<<ROWS / 4, 256, 0, stream>>>(buf5, x, n1g, n1b, buf4);      // dim_in
    G(buf4, 12, bufH, ROWS, 1024, 256, true);             // mlp1 hidden (gelu)
    G(bufH, 13, buf5, ROWS, 256, 1024, false);            // mlp1 out
    ln_k<1><<<ROWS / 4, 256, 0, stream>>>(buf5, buf4, n2g, n2b, buf0);   // dim_send (permuted)

    // ---------------- stage 2: routed attention over TS_D within each (b,seg)
    G(router, 4, bufR, 640, 256, 256, false);             // router q-proj (640 rows)
    G(buf0, 5, buf1, ROWS, 256, 256, false);              // k2
    G(buf0, 6, buf2, ROWS, 256, 256, false);              // v2
    attn_k<10,32,1><<<dim3(1024 * 8), 256, 0, stream>>>(bufR, buf1, buf2, bufS1);
    G(bufS1, 7, bufS2, 10240, 256, 256, false);           // dim_buffer
    G(buf0, 8, buf3, ROWS, 256, 256, false);              // q3
    G(bufS2, 9, bufS1, 10240, 256, 256, false);           // k3
    G(bufS2, 10, buf1, 10240, 256, 256, false);           // v3
    attn_k<32,10,0><<<dim3(1024 * 8), 256, 0, stream>>>(buf3, bufS1, buf1, buf2);
    G(buf2, 11, buf3, ROWS, 256, 256, false);             // dim_receive (o-proj)
    ln_k<0><<<ROWS / 4, 256, 0, stream>>>(buf3, buf0, n3g, n3b, buf4);   // dim_enc
    G(buf4, 14, bufH, ROWS, 1024, 256, true);             // mlp2 hidden (gelu)
    G(bufH, 15, buf5, ROWS, 256, 1024, false);            // mlp2 out
    ln_k<2><<<ROWS / 4, 256, 0, stream>>>(buf5, buf4, n4g, n4b, (float*)d_out);
}

// Round 4
// 742.005 us; speedup vs baseline: 1.1432x; 1.1432x over previous
//
#include <hip/hip_runtime.h>
#include <hip/hip_bf16.h>

#define DIM   256
#define NH    8
#define HE    32
#define ROWS  32768          // B*TS_D*SEG = 16*32*64
#define EPS_LN 1e-3f

typedef float f32x4 __attribute__((ext_vector_type(4)));
typedef short s16x8 __attribute__((ext_vector_type(8)));

__device__ __forceinline__ unsigned short f2bf(float f){
    union { float f; unsigned int u; } v; v.f = f;
    unsigned int u = v.u;
    return (unsigned short)((u + 0x7fffu + ((u >> 16) & 1u)) >> 16);   // RNE
}

__device__ __forceinline__ float gelu_f(float x){
    return 0.5f * x * (1.0f + erff(x * 0.70710678118654752440f));      // exact gelu
}

__device__ __forceinline__ void mfma16(f32x4& acc, s16x8 a, s16x8 b){
    asm volatile("v_mfma_f32_16x16x32_bf16 %0, %1, %2, %0"
                 : "+v"(acc) : "v"(a), "v"(b));
}

__device__ __forceinline__ s16x8 pack8(float4 a, float4 b){
    s16x8 v;
    v[0]=(short)f2bf(a.x); v[1]=(short)f2bf(a.y);
    v[2]=(short)f2bf(a.z); v[3]=(short)f2bf(a.w);
    v[4]=(short)f2bf(b.x); v[5]=(short)f2bf(b.y);
    v[6]=(short)f2bf(b.z); v[7]=(short)f2bf(b.w);
    return v;
}

// ---------------- fused weight transpose + bf16 convert (all 16 weights) ----
struct WtArgs { const float* w[16]; unsigned short* o[16]; };
__global__ __launch_bounds__(256) void transp_all_k(WtArgs a){
    int idx = blockIdx.x * 256 + threadIdx.x;          // 0 .. 1835007
    int wi, rem, K, N;
    if (idx < 786432){ wi = idx >> 16; rem = idx & 65535; K = 256; N = 256; }
    else { int t = idx - 786432; wi = 12 + (t >> 18); rem = t & 262143;
           if ((wi & 1) == 0){ K = 256; N = 1024; } else { K = 1024; N = 256; } }
    int ln = (N == 256) ? 8 : 10;
    int k = rem >> ln, n = rem & (N - 1);
    a.o[wi][n * K + k] = f2bf(a.w[wi][rem]);
}

// ---------------- GEMM: C[M,N] = act(A[M,K] @ W[K,N] + bias) ----------------
// EXACT R1-proven loop structure (load -> LDS write -> barrier -> frags+MFMA
// -> barrier; no cross-barrier register prefetch), scaled to 128x128 tile.
// BK=32, 4 waves 2x2, each wave 64x64 = 4x4 16x16x32 frags.
template<int ACT>
__global__ __launch_bounds__(256) void gemm128_k(const float* __restrict__ A,
        const unsigned short* __restrict__ Wt, const float* __restrict__ bias,
        float* __restrict__ C, int M, int N, int K){
    __shared__ __align__(16) unsigned short As[128 * 40];   // 80B rows (pad 32->40)
    __shared__ __align__(16) unsigned short Bs[128 * 40];
    const int tid  = threadIdx.x;
    const long row0 = (long)blockIdx.x * 128;
    const long col0 = (long)blockIdx.y * 128;
    const int w = tid >> 6, lane = tid & 63;
    const int wm = w >> 1, wn = w & 1;
    const int l15 = lane & 15, g = lane >> 4;
    // staging: thread -> row sr (0..127), k-span [sk, sk+16)
    const int sr = tid >> 1, sk = (tid & 1) << 4;
    const float*          Ap = A  + (row0 + sr) * K + sk;
    const unsigned short* Bp = Wt + (col0 + sr) * K + sk;
    const int sidx = sr * 40 + sk;
    f32x4 acc[4][4];
    #pragma unroll
    for (int i = 0; i < 4; i++)
        #pragma unroll
        for (int jj = 0; jj < 4; jj++) acc[i][jj] = (f32x4){0,0,0,0};
    for (int k0 = 0; k0 < K; k0 += 32){
        float4 a0 = *(const float4*)(Ap + k0);
        float4 a1 = *(const float4*)(Ap + k0 + 4);
        float4 a2 = *(const float4*)(Ap + k0 + 8);
        float4 a3 = *(const float4*)(Ap + k0 + 12);
        s16x8  b0 = *(const s16x8*)(Bp + k0);
        s16x8  b1 = *(const s16x8*)(Bp + k0 + 8);
        *(s16x8*)&As[sidx]     = pack8(a0, a1);
        *(s16x8*)&As[sidx + 8] = pack8(a2, a3);
        *(s16x8*)&Bs[sidx]     = b0;
        *(s16x8*)&Bs[sidx + 8] = b1;
        __syncthreads();
        s16x8 af[4], bf[4];
        #pragma unroll
        for (int mi = 0; mi < 4; mi++)
            af[mi] = *(const s16x8*)&As[(wm * 64 + mi * 16 + l15) * 40 + g * 8];
        #pragma unroll
        for (int ni = 0; ni < 4; ni++)
            bf[ni] = *(const s16x8*)&Bs[(wn * 64 + ni * 16 + l15) * 40 + g * 8];
        #pragma unroll
        for (int mi = 0; mi < 4; mi++)
            #pragma unroll
            for (int ni = 0; ni < 4; ni++)
                mfma16(acc[mi][ni], af[mi], bf[ni]);
        __syncthreads();
    }
    float bb[4];
    #pragma unroll
    for (int ni = 0; ni < 4; ni++) bb[ni] = bias[col0 + wn * 64 + ni * 16 + l15];
    #pragma unroll
    for (int mi = 0; mi < 4; mi++){
        const long grow = row0 + wm * 64 + mi * 16 + g * 4;
        #pragma unroll
        for (int ni = 0; ni < 4; ni++){
            const int gcol = (int)col0 + wn * 64 + ni * 16 + l15;
            #pragma unroll
            for (int r = 0; r < 4; r++){
                float v = acc[mi][ni][r] + bb[ni];
                if (ACT) v = gelu_f(v);
                C[(grow + r) * N + gcol] = v;
            }
        }
    }
}

// ---------------- fused attention (VALU, R1-proven) -------------------------
// QMODE 0: qbase = j*L ; QMODE 1 (router): qbase = (j>>4)*L
template<int L, int S, int QMODE>
__global__ __launch_bounds__(256) void attn_k(const float* __restrict__ Q,
        const float* __restrict__ Kp, const float* __restrict__ Vp,
        float* __restrict__ O){
    __shared__ float Qs[L][36];
    __shared__ float Ks[S][36];
    __shared__ float Vs[S][36];
    __shared__ float Sc[L][S + 1];
    const int j = blockIdx.x >> 3, h = blockIdx.x & 7;
    const int tid = threadIdx.x;
    const long qbase = QMODE ? (long)(j >> 4) * L : (long)j * L;
    const long kbase = (long)j * S;
    const long obase = (long)j * L;
    const int hoff = h * HE;
    for (int idx = tid; idx < L * 8; idx += 256){
        int i = idx >> 3, e4 = (idx & 7) << 2;
        *reinterpret_cast<float4*>(&Qs[i][e4]) =
            *reinterpret_cast<const float4*>(Q + (qbase + i) * DIM + hoff + e4);
    }
    for (int idx = tid; idx < S * 8; idx += 256){
        int i = idx >> 3, e4 = (idx & 7) << 2;
        *reinterpret_cast<float4*>(&Ks[i][e4]) =
            *reinterpret_cast<const float4*>(Kp + (kbase + i) * DIM + hoff + e4);
        *reinterpret_cast<float4*>(&Vs[i][e4]) =
            *reinterpret_cast<const float4*>(Vp + (kbase + i) * DIM + hoff + e4);
    }
    __syncthreads();
    for (int idx = tid; idx < L * S; idx += 256){
        int i = idx / S, jj = idx % S;
        float d = 0.f;
        #pragma unroll
        for (int q4 = 0; q4 < 8; q4++){
            float4 a = *reinterpret_cast<const float4*>(&Qs[i][q4 * 4]);
            float4 b = *reinterpret_cast<const float4*>(&Ks[jj][q4 * 4]);
            d += a.x * b.x + a.y * b.y + a.z * b.z + a.w * b.w;
        }
        Sc[i][jj] = d * 0.17677669529663687f;
    }
    __syncthreads();
    if (tid < L){
        float mx = -1e30f;
        for (int jj = 0; jj < S; jj++) mx = fmaxf(mx, Sc[tid][jj]);
        float s = 0.f;
        for (int jj = 0; jj < S; jj++){ float e = expf(Sc[tid][jj] - mx); Sc[tid][jj] = e; s += e; }
        float inv = 1.f / s;
        for (int jj = 0; jj < S; jj++) Sc[tid][jj] *= inv;
    }
    __syncthreads();
    for (int idx = tid; idx < L * 8; idx += 256){
        int i = idx >> 3, e4 = (idx & 7) << 2;
        float4 o = {0.f, 0.f, 0.f, 0.f};
        for (int jj = 0; jj < S; jj++){
            float s = Sc[i][jj];
            float4 v = *reinterpret_cast<const float4*>(&Vs[jj][e4]);
            o.x += s * v.x; o.y += s * v.y; o.z += s * v.z; o.w += s * v.w;
        }
        *reinterpret_cast<float4*>(O + (obase + i) * DIM + hoff + e4) = o;
    }
}

// ---------------- LayerNorm of (X + R), optional row permutation on write ---
template<int PERM>
__global__ __launch_bounds__(256) void ln_k(const float* __restrict__ X,
        const float* __restrict__ R, const float* __restrict__ g,
        const float* __restrict__ be, float* __restrict__ Y){
    const int wid = threadIdx.x >> 6, lane = threadIdx.x & 63;
    const long row = (long)blockIdx.x * 4 + wid;
    float4 xv = *reinterpret_cast<const float4*>(X + row * DIM + lane * 4);
    float4 rv = *reinterpret_cast<const float4*>(R + row * DIM + lane * 4);
    float4 v = {xv.x + rv.x, xv.y + rv.y, xv.z + rv.z, xv.w + rv.w};
    float s = v.x + v.y + v.z + v.w;
    #pragma unroll
    for (int m = 1; m < 64; m <<= 1) s += __shfl_xor(s, m, 64);
    float mean = s * (1.f / 256.f);
    float dx = v.x - mean, dy = v.y - mean, dz = v.z - mean, dw = v.w - mean;
    float q = dx * dx + dy * dy + dz * dz + dw * dw;
    #pragma unroll
    for (int m = 1; m < 64; m <<= 1) q += __shfl_xor(q, m, 64);
    float rstd = rsqrtf(q * (1.f / 256.f) + EPS_LN);
    float4 gv = *reinterpret_cast<const float4*>(g  + lane * 4);
    float4 bv = *reinterpret_cast<const float4*>(be + lane * 4);
    long rout = row;
    if (PERM == 1){ int b = (int)(row >> 11), rem = (int)row & 2047, t = rem >> 6, sg = rem & 63;
                    rout = (long)b * 2048 + sg * 32 + t; }
    if (PERM == 2){ int b = (int)(row >> 11), rem = (int)row & 2047, sg = rem >> 5, t = rem & 31;
                    rout = (long)b * 2048 + t * 64 + sg; }
    float4 o = { dx * rstd * gv.x + bv.x, dy * rstd * gv.y + bv.y,
                 dz * rstd * gv.z + bv.z, dw * rstd * gv.w + bv.w };
    *reinterpret_cast<float4*>(Y + rout * DIM + lane * 4) = o;
}

extern "C" void kernel_launch(void* const* d_in, const int* in_sizes, int n_in,
                              void* d_out, int out_size, void* d_ws, size_t ws_size,
                              hipStream_t stream){
    const float* x      = (const float*)d_in[0];
    const float* router = (const float*)d_in[1];
    const float* bia[16];
    const int bsel[16] = {3,5,7,9, 11,13,15,17, 19,21,23,25, 35,37,39,41};
    for (int i = 0; i < 16; i++) bia[i] = (const float*)d_in[bsel[i]];
    const float* n1g = (const float*)d_in[26]; const float* n1b = (const float*)d_in[27];
    const float* n2g = (const float*)d_in[28]; const float* n2b = (const float*)d_in[29];
    const float* n3g = (const float*)d_in[30]; const float* n3b = (const float*)d_in[31];
    const float* n4g = (const float*)d_in[32]; const float* n4b = (const float*)d_in[33];

    char* ws = (char*)d_ws;
    const size_t ACTB = (size_t)ROWS * DIM * 4;            // 33.55 MB
    float* buf0 = (float*)(ws);
    float* buf1 = (float*)(ws + 1 * ACTB);
    float* buf2 = (float*)(ws + 2 * ACTB);
    float* buf3 = (float*)(ws + 3 * ACTB);
    float* buf4 = (float*)(ws + 4 * ACTB);
    float* buf5 = (float*)(ws + 5 * ACTB);
    float* bufH = buf0;                                     // 32768x1024 aliases buf0..buf3
    size_t off = 6 * ACTB;
    float* bufS1 = (float*)(ws + off); off += (size_t)10240 * 256 * 4;
    float* bufS2 = (float*)(ws + off); off += (size_t)10240 * 256 * 4;
    float* bufR  = (float*)(ws + off); off += (size_t)640 * 256 * 4;
    unsigned short* wtbase = (unsigned short*)(ws + off);

    // weight order: tq tk tv to sq sk sv so rq rk rv ro m1w1 m1w2 m2w1 m2w2
    const int wsel[16] = {2,4,6,8, 10,12,14,16, 18,20,22,24, 34,36,38,40};
    const int wKs[16]  = {256,256,256,256, 256,256,256,256, 256,256,256,256, 256,1024,256,1024};
    const int wNs[16]  = {256,256,256,256, 256,256,256,256, 256,256,256,256, 1024,256,1024,256};
    unsigned short* wt[16];
    { size_t o = 0;
      for (int i = 0; i < 16; i++){ wt[i] = wtbase + o; o += (size_t)wKs[i] * wNs[i]; } }
    WtArgs wa;
    for (int i = 0; i < 16; i++){ wa.w[i] = (const float*)d_in[wsel[i]]; wa.o[i] = wt[i]; }
    transp_all_k<<<7168, 256, 0, stream>>>(wa);             // 1835008 elems total

    auto G = [&](const float* A, int wi, float* C, int M, int N, int K, bool act){
        dim3 g(M / 128, N / 128);
        if (act) gemm128_k<1><<<g, 256, 0, stream>>>(A, wt[wi], bia[wi], C, M, N, K);
        else     gemm128_k<0><<<g, 256, 0, stream>>>(A, wt[wi], bia[wi], C, M, N, K);
    };

    // ---------------- stage 1: time attention over SEG within each (b, t) ----
    G(x, 0, buf0, ROWS, 256, 256, false);                 // q1
    G(x, 1, buf1, ROWS, 256, 256, false);                 // k1
    G(x, 2, buf2, ROWS, 256, 256, false);                 // v1
    attn_k<64,64,0><<<dim3(512 * 8), 256, 0, stream>>>(buf0, buf1, buf2, buf3);
    G(buf3, 3, buf5, ROWS, 256, 256, false);              // time_enc (o-proj)
    ln_k<0><<<ROWS / 4, 256, 0, stream>>>(buf5, x, n1g, n1b, buf4);      // dim_in
    G(buf4, 12, bufH, ROWS, 1024, 256, true);             // mlp1 hidden (gelu)
    G(bufH, 13, buf5, ROWS, 256, 1024, false);            // mlp1 out
    ln_k<1><<<ROWS / 4, 256, 0, stream>>>(buf5, buf4, n2g, n2b, buf0);   // dim_send (permuted)

    // ---------------- stage 2: routed attention over TS_D within each (b,seg)
    G(router, 4, bufR, 640, 256, 256, false);             // router q-proj
    G(buf0, 5, buf1, ROWS, 256, 256, false);              // k2
    G(buf0, 6, buf2, ROWS, 256, 256, false);              // v2
    attn_k<10,32,1><<<dim3(1024 * 8), 256, 0, stream>>>(bufR, buf1, buf2, bufS1);
    G(bufS1, 7, bufS2, 10240, 256, 256, false);           // dim_buffer
    G(buf0, 8, buf3, ROWS, 256, 256, false);              // q3
    G(bufS2, 9, bufS1, 10240, 256, 256, false);           // k3
    G(bufS2, 10, buf1, 10240, 256, 256, false);           // v3
    attn_k<32,10,0><<<dim3(1024 * 8), 256, 0, stream>>>(buf3, bufS1, buf1, buf2);
    G(buf2, 11, buf3, ROWS, 256, 256, false);             // dim_receive (o-proj)
    ln_k<0><<<ROWS / 4, 256, 0, stream>>>(buf3, buf0, n3g, n3b, buf4);   // dim_enc
    G(buf4, 14, bufH, ROWS, 1024, 256, true);             // mlp2 hidden (gelu)
    G(bufH, 15, buf5, ROWS, 256, 1024, false);            // mlp2 out
    ln_k<2><<<ROWS / 4, 256, 0, stream>>>(buf5, buf4, n4g, n4b, (float*)d_out);
}

// Round 6
// 659.006 us; speedup vs baseline: 1.2872x; 1.1259x over previous
//
#include <hip/hip_runtime.h>
#include <hip/hip_bf16.h>

#define DIM   256
#define NH    8
#define HE    32
#define ROWS  32768          // B*TS_D*SEG = 16*32*64
#define EPS_LN 1e-3f

typedef float f32x4 __attribute__((ext_vector_type(4)));
typedef short s16x8 __attribute__((ext_vector_type(8)));
typedef short s16x4 __attribute__((ext_vector_type(4)));
typedef __bf16 bf16x8 __attribute__((ext_vector_type(8)));

__device__ __forceinline__ unsigned short f2bf(float f){
    union { float f; unsigned int u; } v; v.f = f;
    unsigned int u = v.u;
    return (unsigned short)((u + 0x7fffu + ((u >> 16) & 1u)) >> 16);   // RNE
}

__device__ __forceinline__ float gelu_f(float x){
    return 0.5f * x * (1.0f + erff(x * 0.70710678118654752440f));      // exact gelu
}

// asm MFMA — proven in gemm128_k (operands via ds_read, results read late).
__device__ __forceinline__ void mfma16(f32x4& acc, s16x8 a, s16x8 b){
    asm volatile("v_mfma_f32_16x16x32_bf16 %0, %1, %2, %0"
                 : "+v"(acc) : "v"(a), "v"(b));
}

// builtin MFMA — compiler-scheduled + hazard-protected; used in attn64_k
// where VALU-packed operands / VALU-read results are adjacent to the MFMA.
__device__ __forceinline__ void mfma16i(f32x4& acc, s16x8 a, s16x8 b){
    acc = __builtin_amdgcn_mfma_f32_16x16x32_bf16(
        __builtin_bit_cast(bf16x8, a), __builtin_bit_cast(bf16x8, b), acc, 0, 0, 0);
}

__device__ __forceinline__ s16x8 pack8(float4 a, float4 b){
    s16x8 v;
    v[0]=(short)f2bf(a.x); v[1]=(short)f2bf(a.y);
    v[2]=(short)f2bf(a.z); v[3]=(short)f2bf(a.w);
    v[4]=(short)f2bf(b.x); v[5]=(short)f2bf(b.y);
    v[6]=(short)f2bf(b.z); v[7]=(short)f2bf(b.w);
    return v;
}

// ---------------- fused weight transpose + bf16 convert (all 16 weights) ----
struct WtArgs { const float* w[16]; unsigned short* o[16]; };
__global__ __launch_bounds__(256) void transp_all_k(WtArgs a){
    int idx = blockIdx.x * 256 + threadIdx.x;          // 0 .. 1835007
    int wi, rem, K, N;
    if (idx < 786432){ wi = idx >> 16; rem = idx & 65535; K = 256; N = 256; }
    else { int t = idx - 786432; wi = 12 + (t >> 18); rem = t & 262143;
           if ((wi & 1) == 0){ K = 256; N = 1024; } else { K = 1024; N = 256; } }
    int ln = (N == 256) ? 8 : 10;
    int k = rem >> ln, n = rem & (N - 1);
    a.o[wi][n * K + k] = f2bf(a.w[wi][rem]);
}

// ---------------- GEMM: C[M,N] = act(A[M,K] @ W[K,N] + bias) ----------------
// BYTE-IDENTICAL to R4's passing version.
template<int ACT>
__global__ __launch_bounds__(256) void gemm128_k(const float* __restrict__ A,
        const unsigned short* __restrict__ Wt, const float* __restrict__ bias,
        float* __restrict__ C, int M, int N, int K){
    __shared__ __align__(16) unsigned short As[128 * 40];   // 80B rows (pad 32->40)
    __shared__ __align__(16) unsigned short Bs[128 * 40];
    const int tid  = threadIdx.x;
    const long row0 = (long)blockIdx.x * 128;
    const long col0 = (long)blockIdx.y * 128;
    const int w = tid >> 6, lane = tid & 63;
    const int wm = w >> 1, wn = w & 1;
    const int l15 = lane & 15, g = lane >> 4;
    const int sr = tid >> 1, sk = (tid & 1) << 4;
    const float*          Ap = A  + (row0 + sr) * K + sk;
    const unsigned short* Bp = Wt + (col0 + sr) * K + sk;
    const int sidx = sr * 40 + sk;
    f32x4 acc[4][4];
    #pragma unroll
    for (int i = 0; i < 4; i++)
        #pragma unroll
        for (int jj = 0; jj < 4; jj++) acc[i][jj] = (f32x4){0,0,0,0};
    for (int k0 = 0; k0 < K; k0 += 32){
        float4 a0 = *(const float4*)(Ap + k0);
        float4 a1 = *(const float4*)(Ap + k0 + 4);
        float4 a2 = *(const float4*)(Ap + k0 + 8);
        float4 a3 = *(const float4*)(Ap + k0 + 12);
        s16x8  b0 = *(const s16x8*)(Bp + k0);
        s16x8  b1 = *(const s16x8*)(Bp + k0 + 8);
        *(s16x8*)&As[sidx]     = pack8(a0, a1);
        *(s16x8*)&As[sidx + 8] = pack8(a2, a3);
        *(s16x8*)&Bs[sidx]     = b0;
        *(s16x8*)&Bs[sidx + 8] = b1;
        __syncthreads();
        s16x8 af[4], bf[4];
        #pragma unroll
        for (int mi = 0; mi < 4; mi++)
            af[mi] = *(const s16x8*)&As[(wm * 64 + mi * 16 + l15) * 40 + g * 8];
        #pragma unroll
        for (int ni = 0; ni < 4; ni++)
            bf[ni] = *(const s16x8*)&Bs[(wn * 64 + ni * 16 + l15) * 40 + g * 8];
        #pragma unroll
        for (int mi = 0; mi < 4; mi++)
            #pragma unroll
            for (int ni = 0; ni < 4; ni++)
                mfma16(acc[mi][ni], af[mi], bf[ni]);
        __syncthreads();
    }
    float bb[4];
    #pragma unroll
    for (int ni = 0; ni < 4; ni++) bb[ni] = bias[col0 + wn * 64 + ni * 16 + l15];
    #pragma unroll
    for (int mi = 0; mi < 4; mi++){
        const long grow = row0 + wm * 64 + mi * 16 + g * 4;
        #pragma unroll
        for (int ni = 0; ni < 4; ni++){
            const int gcol = (int)col0 + wn * 64 + ni * 16 + l15;
            #pragma unroll
            for (int r = 0; r < 4; r++){
                float v = acc[mi][ni][r] + bb[ni];
                if (ACT) v = gelu_f(v);
                C[(grow + r) * N + gcol] = v;
            }
        }
    }
}

// ---------------- MFMA attention for L=S=64 (time stage): 1 wave/(j,h) ------
// Uses BUILTIN MFMA (hazard-protected) — the only change vs R5.
__global__ __launch_bounds__(64) void attn64_k(const float* __restrict__ Q,
        const float* __restrict__ Kp, const float* __restrict__ Vp,
        float* __restrict__ O){
    __shared__ __align__(16) unsigned short P[64][72];     // P[q][s] bf16
    const int j = blockIdx.x >> 3, h = blockIdx.x & 7;
    const int lane = threadIdx.x;
    const int l15 = lane & 15, g = lane >> 4;
    const long base = (long)j * 64 * DIM;
    const int hoff = h * HE;
    const float scale = 0.17677669529663687f;   // 1/sqrt(32)
    // ---- swapped QK^T: st[sb][qb] holds S^T[s][q], s=sb*16+g*4+r, q=qb*16+l15
    s16x8 kf[4], qf[4];
    #pragma unroll
    for (int b = 0; b < 4; b++){
        const float* kp = Kp + base + (long)(b * 16 + l15) * DIM + hoff + g * 8;
        kf[b] = pack8(*(const float4*)kp, *(const float4*)(kp + 4));
        const float* qp = Q + base + (long)(b * 16 + l15) * DIM + hoff + g * 8;
        qf[b] = pack8(*(const float4*)qp, *(const float4*)(qp + 4));
    }
    f32x4 st[4][4];
    #pragma unroll
    for (int sb = 0; sb < 4; sb++)
        #pragma unroll
        for (int qb = 0; qb < 4; qb++) st[sb][qb] = (f32x4){0,0,0,0};
    #pragma unroll
    for (int sb = 0; sb < 4; sb++)
        #pragma unroll
        for (int qb = 0; qb < 4; qb++) mfma16i(st[sb][qb], kf[sb], qf[qb]);
    #pragma unroll
    for (int sb = 0; sb < 4; sb++)
        #pragma unroll
        for (int qb = 0; qb < 4; qb++)
            #pragma unroll
            for (int r = 0; r < 4; r++) st[sb][qb][r] *= scale;
    // ---- softmax over s for each q-column: local 16 values + reduce over g
    #pragma unroll
    for (int qb = 0; qb < 4; qb++){
        float mx = -1e30f;
        #pragma unroll
        for (int sb = 0; sb < 4; sb++)
            #pragma unroll
            for (int r = 0; r < 4; r++) mx = fmaxf(mx, st[sb][qb][r]);
        mx = fmaxf(mx, __shfl_xor(mx, 16, 64));
        mx = fmaxf(mx, __shfl_xor(mx, 32, 64));
        float sum = 0.f;
        #pragma unroll
        for (int sb = 0; sb < 4; sb++)
            #pragma unroll
            for (int r = 0; r < 4; r++){
                float e = expf(st[sb][qb][r] - mx);
                st[sb][qb][r] = e; sum += e;
            }
        sum += __shfl_xor(sum, 16, 64);
        sum += __shfl_xor(sum, 32, 64);
        float inv = 1.f / sum;
        const int q = qb * 16 + l15;
        #pragma unroll
        for (int sb = 0; sb < 4; sb++){
            s16x4 p4;
            #pragma unroll
            for (int r = 0; r < 4; r++) p4[r] = (short)f2bf(st[sb][qb][r] * inv);
            *(s16x4*)&P[q][sb * 16 + g * 4] = p4;
        }
    }
    __syncthreads();
    // ---- PV: O[q][e] = sum_s P[q][s] V[s][e], two K=32 steps over s
    f32x4 o[4][2];
    #pragma unroll
    for (int qb = 0; qb < 4; qb++)
        #pragma unroll
        for (int eb = 0; eb < 2; eb++) o[qb][eb] = (f32x4){0,0,0,0};
    #pragma unroll
    for (int ksl = 0; ksl < 2; ksl++){
        s16x8 pf[4], vf[2];
        #pragma unroll
        for (int qb = 0; qb < 4; qb++)
            pf[qb] = *(const s16x8*)&P[qb * 16 + l15][ksl * 32 + g * 8];
        #pragma unroll
        for (int eb = 0; eb < 2; eb++){
            const float* vp = Vp + base + (long)(ksl * 32 + g * 8) * DIM + hoff + eb * 16 + l15;
            s16x8 vv;
            #pragma unroll
            for (int jj = 0; jj < 8; jj++) vv[jj] = (short)f2bf(vp[(long)jj * DIM]);
            vf[eb] = vv;
        }
        #pragma unroll
        for (int qb = 0; qb < 4; qb++)
            #pragma unroll
            for (int eb = 0; eb < 2; eb++) mfma16i(o[qb][eb], pf[qb], vf[eb]);
    }
    #pragma unroll
    for (int qb = 0; qb < 4; qb++)
        #pragma unroll
        for (int eb = 0; eb < 2; eb++){
            const int q = qb * 16 + g * 4;
            float* op = O + base + (long)q * DIM + hoff + eb * 16 + l15;
            #pragma unroll
            for (int r = 0; r < 4; r++) op[(long)r * DIM] = o[qb][eb][r];
        }
}

// ---------------- fused attention (small shapes): VALU version --------------
// QMODE 0: qbase = j*L ; QMODE 1 (router): qbase = (j>>4)*L
template<int L, int S, int QMODE>
__global__ __launch_bounds__(256) void attn_k(const float* __restrict__ Q,
        const float* __restrict__ Kp, const float* __restrict__ Vp,
        float* __restrict__ O){
    __shared__ float Qs[L][36];
    __shared__ float Ks[S][36];
    __shared__ float Vs[S][36];
    __shared__ float Sc[L][S + 1];
    const int j = blockIdx.x >> 3, h = blockIdx.x & 7;
    const int tid = threadIdx.x;
    const long qbase = QMODE ? (long)(j >> 4) * L : (long)j * L;
    const long kbase = (long)j * S;
    const long obase = (long)j * L;
    const int hoff = h * HE;
    for (int idx = tid; idx < L * 8; idx += 256){
        int i = idx >> 3, e4 = (idx & 7) << 2;
        *reinterpret_cast<float4*>(&Qs[i][e4]) =
            *reinterpret_cast<const float4*>(Q + (qbase + i) * DIM + hoff + e4);
    }
    for (int idx = tid; idx < S * 8; idx += 256){
        int i = idx >> 3, e4 = (idx & 7) << 2;
        *reinterpret_cast<float4*>(&Ks[i][e4]) =
            *reinterpret_cast<const float4*>(Kp + (kbase + i) * DIM + hoff + e4);
        *reinterpret_cast<float4*>(&Vs[i][e4]) =
            *reinterpret_cast<const float4*>(Vp + (kbase + i) * DIM + hoff + e4);
    }
    __syncthreads();
    for (int idx = tid; idx < L * S; idx += 256){
        int i = idx / S, jj = idx % S;
        float d = 0.f;
        #pragma unroll
        for (int q4 = 0; q4 < 8; q4++){
            float4 a = *reinterpret_cast<const float4*>(&Qs[i][q4 * 4]);
            float4 b = *reinterpret_cast<const float4*>(&Ks[jj][q4 * 4]);
            d += a.x * b.x + a.y * b.y + a.z * b.z + a.w * b.w;
        }
        Sc[i][jj] = d * 0.17677669529663687f;
    }
    __syncthreads();
    if (tid < L){
        float mx = -1e30f;
        for (int jj = 0; jj < S; jj++) mx = fmaxf(mx, Sc[tid][jj]);
        float s = 0.f;
        for (int jj = 0; jj < S; jj++){ float e = expf(Sc[tid][jj] - mx); Sc[tid][jj] = e; s += e; }
        float inv = 1.f / s;
        for (int jj = 0; jj < S; jj++) Sc[tid][jj] *= inv;
    }
    __syncthreads();
    for (int idx = tid; idx < L * 8; idx += 256){
        int i = idx >> 3, e4 = (idx & 7) << 2;
        float4 o = {0.f, 0.f, 0.f, 0.f};
        for (int jj = 0; jj < S; jj++){
            float s = Sc[i][jj];
            float4 v = *reinterpret_cast<const float4*>(&Vs[jj][e4]);
            o.x += s * v.x; o.y += s * v.y; o.z += s * v.z; o.w += s * v.w;
        }
        *reinterpret_cast<float4*>(O + (obase + i) * DIM + hoff + e4) = o;
    }
}

// ---------------- LayerNorm of (X + R), optional row permutation on write ---
template<int PERM>
__global__ __launch_bounds__(256) void ln_k(const float* __restrict__ X,
        const float* __restrict__ R, const float* __restrict__ g,
        const float* __restrict__ be, float* __restrict__ Y){
    const int wid = threadIdx.x >> 6, lane = threadIdx.x & 63;
    const long row = (long)blockIdx.x * 4 + wid;
    float4 xv = *reinterpret_cast<const float4*>(X + row * DIM + lane * 4);
    float4 rv = *reinterpret_cast<const float4*>(R + row * DIM + lane * 4);
    float4 v = {xv.x + rv.x, xv.y + rv.y, xv.z + rv.z, xv.w + rv.w};
    float s = v.x + v.y + v.z + v.w;
    #pragma unroll
    for (int m = 1; m < 64; m <<= 1) s += __shfl_xor(s, m, 64);
    float mean = s * (1.f / 256.f);
    float dx = v.x - mean, dy = v.y - mean, dz = v.z - mean, dw = v.w - mean;
    float q = dx * dx + dy * dy + dz * dz + dw * dw;
    #pragma unroll
    for (int m = 1; m < 64; m <<= 1) q += __shfl_xor(q, m, 64);
    float rstd = rsqrtf(q * (1.f / 256.f) + EPS_LN);
    float4 gv = *reinterpret_cast<const float4*>(g  + lane * 4);
    float4 bv = *reinterpret_cast<const float4*>(be + lane * 4);
    long rout = row;
    if (PERM == 1){ int b = (int)(row >> 11), rem = (int)row & 2047, t = rem >> 6, sg = rem & 63;
                    rout = (long)b * 2048 + sg * 32 + t; }
    if (PERM == 2){ int b = (int)(row >> 11), rem = (int)row & 2047, sg = rem >> 5, t = rem & 31;
                    rout = (long)b * 2048 + t * 64 + sg; }
    float4 o = { dx * rstd * gv.x + bv.x, dy * rstd * gv.y + bv.y,
                 dz * rstd * gv.z + bv.z, dw * rstd * gv.w + bv.w };
    *reinterpret_cast<float4*>(Y + rout * DIM + lane * 4) = o;
}

extern "C" void kernel_launch(void* const* d_in, const int* in_sizes, int n_in,
                              void* d_out, int out_size, void* d_ws, size_t ws_size,
                              hipStream_t stream){
    const float* x      = (const float*)d_in[0];
    const float* router = (const float*)d_in[1];
    const float* bia[16];
    const int bsel[16] = {3,5,7,9, 11,13,15,17, 19,21,23,25, 35,37,39,41};
    for (int i = 0; i < 16; i++) bia[i] = (const float*)d_in[bsel[i]];
    const float* n1g = (const float*)d_in[26]; const float* n1b = (const float*)d_in[27];
    const float* n2g = (const float*)d_in[28]; const float* n2b = (const float*)d_in[29];
    const float* n3g = (const float*)d_in[30]; const float* n3b = (const float*)d_in[31];
    const float* n4g = (const float*)d_in[32]; const float* n4b = (const float*)d_in[33];

    char* ws = (char*)d_ws;
    const size_t ACTB = (size_t)ROWS * DIM * 4;            // 33.55 MB
    float* buf0 = (float*)(ws);
    float* buf1 = (float*)(ws + 1 * ACTB);
    float* buf2 = (float*)(ws + 2 * ACTB);
    float* buf3 = (float*)(ws + 3 * ACTB);
    float* buf4 = (float*)(ws + 4 * ACTB);
    float* buf5 = (float*)(ws + 5 * ACTB);
    float* bufH = buf0;                                     // 32768x1024 aliases buf0..buf3
    size_t off = 6 * ACTB;
    float* bufS1 = (float*)(ws + off); off += (size_t)10240 * 256 * 4;
    float* bufS2 = (float*)(ws + off); off += (size_t)10240 * 256 * 4;
    float* bufR  = (float*)(ws + off); off += (size_t)640 * 256 * 4;
    unsigned short* wtbase = (unsigned short*)(ws + off);

    // weight order: tq tk tv to sq sk sv so rq rk rv ro m1w1 m1w2 m2w1 m2w2
    const int wsel[16] = {2,4,6,8, 10,12,14,16, 18,20,22,24, 34,36,38,40};
    const int wKs[16]  = {256,256,256,256, 256,256,256,256, 256,256,256,256, 256,1024,256,1024};
    const int wNs[16]  = {256,256,256,256, 256,256,256,256, 256,256,256,256, 1024,256,1024,256};
    unsigned short* wt[16];
    { size_t o = 0;
      for (int i = 0; i < 16; i++){ wt[i] = wtbase + o; o += (size_t)wKs[i] * wNs[i]; } }
    WtArgs wa;
    for (int i = 0; i < 16; i++){ wa.w[i] = (const float*)d_in[wsel[i]]; wa.o[i] = wt[i]; }
    transp_all_k<<<7168, 256, 0, stream>>>(wa);             // 1835008 elems total

    auto G = [&](const float* A, int wi, float* C, int M, int N, int K, bool act){
        dim3 g(M / 128, N / 128);
        if (act) gemm128_k<1><<<g, 256, 0, stream>>>(A, wt[wi], bia[wi], C, M, N, K);
        else     gemm128_k<0><<<g, 256, 0, stream>>>(A, wt[wi], bia[wi], C, M, N, K);
    };

    // ---------------- stage 1: time attention over SEG within each (b, t) ----
    G(x, 0, buf0, ROWS, 256, 256, false);                 // q1
    G(x, 1, buf1, ROWS, 256, 256, false);                 // k1
    G(x, 2, buf2, ROWS, 256, 256, false);                 // v1
    attn64_k<<<dim3(512 * 8), 64, 0, stream>>>(buf0, buf1, buf2, buf3);
    G(buf3, 3, buf5, ROWS, 256, 256, false);              // time_enc (o-proj)
    ln_k<0><<<ROWS / 4, 256, 0, stream>>>(buf5, x, n1g, n1b, buf4);      // dim_in
    G(buf4, 12, bufH, ROWS, 1024, 256, true);             // mlp1 hidden (gelu)
    G(bufH, 13, buf5, ROWS, 256, 1024, false);            // mlp1 out
    ln_k<1><<<ROWS / 4, 256, 0, stream>>>(buf5, buf4, n2g, n2b, buf0);   // dim_send (permuted)

    // ---------------- stage 2: routed attention over TS_D within each (b,seg)
    G(router, 4, bufR, 640, 256, 256, false);             // router q-proj
    G(buf0, 5, buf1, ROWS, 256, 256, false);              // k2
    G(buf0, 6, buf2, ROWS, 256, 256, false);              // v2
    attn_k<10,32,1><<<dim3(1024 * 8), 256, 0, stream>>>(bufR, buf1, buf2, bufS1);
    G(bufS1, 7, bufS2, 10240, 256, 256, false);           // dim_buffer
    G(buf0, 8, buf3, ROWS, 256, 256, false);              // q3
    G(bufS2, 9, bufS1, 10240, 256, 256, false);           // k3
    G(bufS2, 10, buf1, 10240, 256, 256, false);           // v3
    attn_k<32,10,0><<<dim3(1024 * 8), 256, 0, stream>>>(buf3, bufS1, buf1, buf2);
    G(buf2, 11, buf3, ROWS, 256, 256, false);             // dim_receive (o-proj)
    ln_k<0><<<ROWS / 4, 256, 0, stream>>>(buf3, buf0, n3g, n3b, buf4);   // dim_enc
    G(buf4, 14, bufH, ROWS, 1024, 256, true);             // mlp2 hidden (gelu)
    G(bufH, 15, buf5, ROWS, 256, 1024, false);            // mlp2 out
    ln_k<2><<<ROWS / 4, 256, 0, stream>>>(buf5, buf4, n4g, n4b, (float*)d_out);
}

// Round 7
// 617.651 us; speedup vs baseline: 1.3734x; 1.0670x over previous
//
#include <hip/hip_runtime.h>
#include <hip/hip_bf16.h>

#define DIM   256
#define NH    8
#define HE    32
#define ROWS  32768          // B*TS_D*SEG = 16*32*64
#define EPS_LN 1e-3f

typedef float f32x4 __attribute__((ext_vector_type(4)));
typedef short s16x8 __attribute__((ext_vector_type(8)));
typedef short s16x4 __attribute__((ext_vector_type(4)));
typedef __bf16 bf16x8 __attribute__((ext_vector_type(8)));

__device__ __forceinline__ unsigned short f2bf(float f){
    union { float f; unsigned int u; } v; v.f = f;
    unsigned int u = v.u;
    return (unsigned short)((u + 0x7fffu + ((u >> 16) & 1u)) >> 16);   // RNE
}

__device__ __forceinline__ float gelu_f(float x){
    return 0.5f * x * (1.0f + erff(x * 0.70710678118654752440f));      // exact gelu
}

// builtin MFMA only — compiler-scheduled + hazard-protected (asm MFMA caused
// the R2/R3/R5 NaNs via missing VALU<->MFMA hazard waits inside INLINEASM).
__device__ __forceinline__ void mfma16i(f32x4& acc, s16x8 a, s16x8 b){
    acc = __builtin_amdgcn_mfma_f32_16x16x32_bf16(
        __builtin_bit_cast(bf16x8, a), __builtin_bit_cast(bf16x8, b), acc, 0, 0, 0);
}

__device__ __forceinline__ s16x8 pack8(float4 a, float4 b){
    s16x8 v;
    v[0]=(short)f2bf(a.x); v[1]=(short)f2bf(a.y);
    v[2]=(short)f2bf(a.z); v[3]=(short)f2bf(a.w);
    v[4]=(short)f2bf(b.x); v[5]=(short)f2bf(b.y);
    v[6]=(short)f2bf(b.z); v[7]=(short)f2bf(b.w);
    return v;
}

// async global->LDS, 16B/lane; LDS dest = wave-uniform base + lane*16
__device__ __forceinline__ void gld16(const unsigned short* g, unsigned short* l){
    __builtin_amdgcn_global_load_lds(
        (const __attribute__((address_space(1))) unsigned int*)g,
        (__attribute__((address_space(3))) unsigned int*)l, 16, 0, 0);
}

// ---------------- fused weight transpose + bf16 convert (all 16 weights) ----
struct WtArgs { const float* w[16]; unsigned short* o[16]; };
__global__ __launch_bounds__(256) void transp_all_k(WtArgs a){
    int idx = blockIdx.x * 256 + threadIdx.x;          // 0 .. 1835007
    int wi, rem, K, N;
    if (idx < 786432){ wi = idx >> 16; rem = idx & 65535; K = 256; N = 256; }
    else { int t = idx - 786432; wi = 12 + (t >> 18); rem = t & 262143;
           if ((wi & 1) == 0){ K = 256; N = 1024; } else { K = 1024; N = 256; } }
    int ln = (N == 256) ? 8 : 10;
    int k = rem >> ln, n = rem & (N - 1);
    a.o[wi][n * K + k] = f2bf(a.w[wi][rem]);
}

// ---------------- concat biases for fused GEMM groups -----------------------
struct BcArgs { const float* src[8]; float* dst; };
__global__ __launch_bounds__(256) void bias_cat_k(BcArgs a){
    int idx = blockIdx.x * 256 + threadIdx.x;          // 0..2047
    a.dst[idx] = a.src[idx >> 8][idx & 255];
}

// ---------------- pipelined GEMM: C = act(A @ W + bias) ---------------------
// 128x128 tile, BK=32, double-buffered LDS, ONE barrier per K-step.
// B always staged via global_load_lds (bf16 NxK). A: fp32 reg-staged or bf16
// via global_load_lds. SPLIT: N covers 2-3 concatenated weights, C written to
// per-256-col output buffers (ldc=256).
template<int ACT, int ABF16, int CBF16, int SPLIT>
__global__ __launch_bounds__(256) void gemm_k(const void* __restrict__ Av,
        const unsigned short* __restrict__ Wt, const float* __restrict__ bias,
        void* C0, void* C1, void* C2, int M, int N, int K){
    __shared__ __align__(16) unsigned short As[2][128 * 32];   // linear 64B rows
    __shared__ __align__(16) unsigned short Bs[2][128 * 32];
    const int tid  = threadIdx.x;
    const long row0 = (long)blockIdx.x * 128;
    const long col0 = (long)blockIdx.y * 128;
    const int w = tid >> 6, lane = tid & 63;
    const int wm = w >> 1, wn = w & 1;
    const int l15 = lane & 15, g = lane >> 4;
    // B staging: wave w covers tile rows [32w, 32w+32)
    const unsigned short* Bg = Wt + (size_t)(col0 + 32 * w + (lane >> 2)) * K + (lane & 3) * 8;
    // A staging (fp32 path): thread -> row sr, k-span [sk, sk+16)
    const int sr = tid >> 1, sk = (tid & 1) << 4;
    const float* Ap = (const float*)Av + (size_t)(row0 + sr) * K + sk;
    // A staging (bf16 path): like B
    const unsigned short* Ag = (const unsigned short*)Av +
        (size_t)(row0 + 32 * w + (lane >> 2)) * K + (lane & 3) * 8;

    auto stage = [&](int kk, int nb){
        gld16(Bg + kk, &Bs[nb][(32 * w) * 32]);
        gld16(Bg + 16 * K + kk, &Bs[nb][(32 * w + 16) * 32]);
        if (ABF16){
            gld16(Ag + kk, &As[nb][(32 * w) * 32]);
            gld16(Ag + 16 * K + kk, &As[nb][(32 * w + 16) * 32]);
        } else {
            float4 a0 = *(const float4*)(Ap + kk);
            float4 a1 = *(const float4*)(Ap + kk + 4);
            float4 a2 = *(const float4*)(Ap + kk + 8);
            float4 a3 = *(const float4*)(Ap + kk + 12);
            *(s16x8*)&As[nb][sr * 32 + sk]     = pack8(a0, a1);
            *(s16x8*)&As[nb][sr * 32 + sk + 8] = pack8(a2, a3);
        }
    };

    f32x4 acc[4][4];
    #pragma unroll
    for (int i = 0; i < 4; i++)
        #pragma unroll
        for (int jj = 0; jj < 4; jj++) acc[i][jj] = (f32x4){0,0,0,0};

    stage(0, 0);
    __syncthreads();
    int cur = 0;
    for (int k0 = 0; k0 < K; k0 += 32){
        if (k0 + 32 < K) stage(k0 + 32, cur ^ 1);
        s16x8 af[4], bf[4];
        #pragma unroll
        for (int mi = 0; mi < 4; mi++)
            af[mi] = *(const s16x8*)&As[cur][(wm * 64 + mi * 16 + l15) * 32 + g * 8];
        #pragma unroll
        for (int ni = 0; ni < 4; ni++)
            bf[ni] = *(const s16x8*)&Bs[cur][(wn * 64 + ni * 16 + l15) * 32 + g * 8];
        #pragma unroll
        for (int mi = 0; mi < 4; mi++)
            #pragma unroll
            for (int ni = 0; ni < 4; ni++)
                mfma16i(acc[mi][ni], af[mi], bf[ni]);
        __syncthreads();
        cur ^= 1;
    }
    // epilogue
    const int sel = SPLIT ? (int)(col0 >> 8) : 0;
    void* Cp = SPLIT ? (sel == 0 ? C0 : (sel == 1 ? C1 : C2)) : C0;
    const int ldc = SPLIT ? 256 : N;
    float bb[4];
    #pragma unroll
    for (int ni = 0; ni < 4; ni++) bb[ni] = bias[col0 + wn * 64 + ni * 16 + l15];
    #pragma unroll
    for (int mi = 0; mi < 4; mi++){
        const long grow = row0 + wm * 64 + mi * 16 + g * 4;
        #pragma unroll
        for (int ni = 0; ni < 4; ni++){
            int gcol = (int)col0 + wn * 64 + ni * 16 + l15;
            int lcol = SPLIT ? (gcol & 255) : gcol;
            #pragma unroll
            for (int r = 0; r < 4; r++){
                float v = acc[mi][ni][r] + bb[ni];
                if (ACT) v = gelu_f(v);
                if (CBF16) ((unsigned short*)Cp)[(grow + r) * ldc + lcol] = f2bf(v);
                else       ((float*)Cp)[(grow + r) * ldc + lcol] = v;
            }
        }
    }
}

// ---------------- MFMA attention for L=S=64 (time stage): 1 wave/(j,h) ------
__global__ __launch_bounds__(64) void attn64_k(const float* __restrict__ Q,
        const float* __restrict__ Kp, const float* __restrict__ Vp,
        float* __restrict__ O){
    __shared__ __align__(16) unsigned short P[64][72];     // P[q][s] bf16
    const int j = blockIdx.x >> 3, h = blockIdx.x & 7;
    const int lane = threadIdx.x;
    const int l15 = lane & 15, g = lane >> 4;
    const long base = (long)j * 64 * DIM;
    const int hoff = h * HE;
    const float scale = 0.17677669529663687f;   // 1/sqrt(32)
    s16x8 kf[4], qf[4];
    #pragma unroll
    for (int b = 0; b < 4; b++){
        const float* kp = Kp + base + (long)(b * 16 + l15) * DIM + hoff + g * 8;
        kf[b] = pack8(*(const float4*)kp, *(const float4*)(kp + 4));
        const float* qp = Q + base + (long)(b * 16 + l15) * DIM + hoff + g * 8;
        qf[b] = pack8(*(const float4*)qp, *(const float4*)(qp + 4));
    }
    f32x4 st[4][4];
    #pragma unroll
    for (int sb = 0; sb < 4; sb++)
        #pragma unroll
        for (int qb = 0; qb < 4; qb++) st[sb][qb] = (f32x4){0,0,0,0};
    #pragma unroll
    for (int sb = 0; sb < 4; sb++)
        #pragma unroll
        for (int qb = 0; qb < 4; qb++) mfma16i(st[sb][qb], kf[sb], qf[qb]);
    #pragma unroll
    for (int sb = 0; sb < 4; sb++)
        #pragma unroll
        for (int qb = 0; qb < 4; qb++)
            #pragma unroll
            for (int r = 0; r < 4; r++) st[sb][qb][r] *= scale;
    #pragma unroll
    for (int qb = 0; qb < 4; qb++){
        float mx = -1e30f;
        #pragma unroll
        for (int sb = 0; sb < 4; sb++)
            #pragma unroll
            for (int r = 0; r < 4; r++) mx = fmaxf(mx, st[sb][qb][r]);
        mx = fmaxf(mx, __shfl_xor(mx, 16, 64));
        mx = fmaxf(mx, __shfl_xor(mx, 32, 64));
        float sum = 0.f;
        #pragma unroll
        for (int sb = 0; sb < 4; sb++)
            #pragma unroll
            for (int r = 0; r < 4; r++){
                float e = expf(st[sb][qb][r] - mx);
                st[sb][qb][r] = e; sum += e;
            }
        sum += __shfl_xor(sum, 16, 64);
        sum += __shfl_xor(sum, 32, 64);
        float inv = 1.f / sum;
        const int q = qb * 16 + l15;
        #pragma unroll
        for (int sb = 0; sb < 4; sb++){
            s16x4 p4;
            #pragma unroll
            for (int r = 0; r < 4; r++) p4[r] = (short)f2bf(st[sb][qb][r] * inv);
            *(s16x4*)&P[q][sb * 16 + g * 4] = p4;
        }
    }
    __syncthreads();
    f32x4 o[4][2];
    #pragma unroll
    for (int qb = 0; qb < 4; qb++)
        #pragma unroll
        for (int eb = 0; eb < 2; eb++) o[qb][eb] = (f32x4){0,0,0,0};
    #pragma unroll
    for (int ksl = 0; ksl < 2; ksl++){
        s16x8 pf[4], vf[2];
        #pragma unroll
        for (int qb = 0; qb < 4; qb++)
            pf[qb] = *(const s16x8*)&P[qb * 16 + l15][ksl * 32 + g * 8];
        #pragma unroll
        for (int eb = 0; eb < 2; eb++){
            const float* vp = Vp + base + (long)(ksl * 32 + g * 8) * DIM + hoff + eb * 16 + l15;
            s16x8 vv;
            #pragma unroll
            for (int jj = 0; jj < 8; jj++) vv[jj] = (short)f2bf(vp[(long)jj * DIM]);
            vf[eb] = vv;
        }
        #pragma unroll
        for (int qb = 0; qb < 4; qb++)
            #pragma unroll
            for (int eb = 0; eb < 2; eb++) mfma16i(o[qb][eb], pf[qb], vf[eb]);
    }
    #pragma unroll
    for (int qb = 0; qb < 4; qb++)
        #pragma unroll
        for (int eb = 0; eb < 2; eb++){
            const int q = qb * 16 + g * 4;
            float* op = O + base + (long)q * DIM + hoff + eb * 16 + l15;
            #pragma unroll
            for (int r = 0; r < 4; r++) op[(long)r * DIM] = o[qb][eb][r];
        }
}

// ---------------- fused attention (small shapes): VALU version --------------
template<int L, int S, int QMODE>
__global__ __launch_bounds__(256) void attn_k(const float* __restrict__ Q,
        const float* __restrict__ Kp, const float* __restrict__ Vp,
        float* __restrict__ O){
    __shared__ float Qs[L][36];
    __shared__ float Ks[S][36];
    __shared__ float Vs[S][36];
    __shared__ float Sc[L][S + 1];
    const int j = blockIdx.x >> 3, h = blockIdx.x & 7;
    const int tid = threadIdx.x;
    const long qbase = QMODE ? (long)(j >> 4) * L : (long)j * L;
    const long kbase = (long)j * S;
    const long obase = (long)j * L;
    const int hoff = h * HE;
    for (int idx = tid; idx < L * 8; idx += 256){
        int i = idx >> 3, e4 = (idx & 7) << 2;
        *reinterpret_cast<float4*>(&Qs[i][e4]) =
            *reinterpret_cast<const float4*>(Q + (qbase + i) * DIM + hoff + e4);
    }
    for (int idx = tid; idx < S * 8; idx += 256){
        int i = idx >> 3, e4 = (idx & 7) << 2;
        *reinterpret_cast<float4*>(&Ks[i][e4]) =
            *reinterpret_cast<const float4*>(Kp + (kbase + i) * DIM + hoff + e4);
        *reinterpret_cast<float4*>(&Vs[i][e4]) =
            *reinterpret_cast<const float4*>(Vp + (kbase + i) * DIM + hoff + e4);
    }
    __syncthreads();
    for (int idx = tid; idx < L * S; idx += 256){
        int i = idx / S, jj = idx % S;
        float d = 0.f;
        #pragma unroll
        for (int q4 = 0; q4 < 8; q4++){
            float4 a = *reinterpret_cast<const float4*>(&Qs[i][q4 * 4]);
            float4 b = *reinterpret_cast<const float4*>(&Ks[jj][q4 * 4]);
            d += a.x * b.x + a.y * b.y + a.z * b.z + a.w * b.w;
        }
        Sc[i][jj] = d * 0.17677669529663687f;
    }
    __syncthreads();
    if (tid < L){
        float mx = -1e30f;
        for (int jj = 0; jj < S; jj++) mx = fmaxf(mx, Sc[tid][jj]);
        float s = 0.f;
        for (int jj = 0; jj < S; jj++){ float e = expf(Sc[tid][jj] - mx); Sc[tid][jj] = e; s += e; }
        float inv = 1.f / s;
        for (int jj = 0; jj < S; jj++) Sc[tid][jj] *= inv;
    }
    __syncthreads();
    for (int idx = tid; idx < L * 8; idx += 256){
        int i = idx >> 3, e4 = (idx & 7) << 2;
        float4 o = {0.f, 0.f, 0.f, 0.f};
        for (int jj = 0; jj < S; jj++){
            float s = Sc[i][jj];
            float4 v = *reinterpret_cast<const float4*>(&Vs[jj][e4]);
            o.x += s * v.x; o.y += s * v.y; o.z += s * v.z; o.w += s * v.w;
        }
        *reinterpret_cast<float4*>(O + (obase + i) * DIM + hoff + e4) = o;
    }
}

// ---------------- LayerNorm of (X + R), optional row permutation on write ---
template<int PERM>
__global__ __launch_bounds__(256) void ln_k(const float* __restrict__ X,
        const float* __restrict__ R, const float* __restrict__ g,
        const float* __restrict__ be, float* __restrict__ Y){
    const int wid = threadIdx.x >> 6, lane = threadIdx.x & 63;
    const long row = (long)blockIdx.x * 4 + wid;
    float4 xv = *reinterpret_cast<const float4*>(X + row * DIM + lane * 4);
    float4 rv = *reinterpret_cast<const float4*>(R + row * DIM + lane * 4);
    float4 v = {xv.x + rv.x, xv.y + rv.y, xv.z + rv.z, xv.w + rv.w};
    float s = v.x + v.y + v.z + v.w;
    #pragma unroll
    for (int m = 1; m < 64; m <<= 1) s += __shfl_xor(s, m, 64);
    float mean = s * (1.f / 256.f);
    float dx = v.x - mean, dy = v.y - mean, dz = v.z - mean, dw = v.w - mean;
    float q = dx * dx + dy * dy + dz * dz + dw * dw;
    #pragma unroll
    for (int m = 1; m < 64; m <<= 1) q += __shfl_xor(q, m, 64);
    float rstd = rsqrtf(q * (1.f / 256.f) + EPS_LN);
    float4 gv = *reinterpret_cast<const float4*>(g  + lane * 4);
    float4 bv = *reinterpret_cast<const float4*>(be + lane * 4);
    long rout = row;
    if (PERM == 1){ int b = (int)(row >> 11), rem = (int)row & 2047, t = rem >> 6, sg = rem & 63;
                    rout = (long)b * 2048 + sg * 32 + t; }
    if (PERM == 2){ int b = (int)(row >> 11), rem = (int)row & 2047, sg = rem >> 5, t = rem & 31;
                    rout = (long)b * 2048 + t * 64 + sg; }
    float4 o = { dx * rstd * gv.x + bv.x, dy * rstd * gv.y + bv.y,
                 dz * rstd * gv.z + bv.z, dw * rstd * gv.w + bv.w };
    *reinterpret_cast<float4*>(Y + rout * DIM + lane * 4) = o;
}

extern "C" void kernel_launch(void* const* d_in, const int* in_sizes, int n_in,
                              void* d_out, int out_size, void* d_ws, size_t ws_size,
                              hipStream_t stream){
    const float* x      = (const float*)d_in[0];
    const float* router = (const float*)d_in[1];
    const float* n1g = (const float*)d_in[26]; const float* n1b = (const float*)d_in[27];
    const float* n2g = (const float*)d_in[28]; const float* n2b = (const float*)d_in[29];
    const float* n3g = (const float*)d_in[30]; const float* n3b = (const float*)d_in[31];
    const float* n4g = (const float*)d_in[32]; const float* n4b = (const float*)d_in[33];

    char* ws = (char*)d_ws;
    const size_t ACTB = (size_t)ROWS * DIM * 4;            // 33.55 MB
    float* buf0 = (float*)(ws);
    float* buf1 = (float*)(ws + 1 * ACTB);
    float* buf2 = (float*)(ws + 2 * ACTB);
    float* buf3 = (float*)(ws + 3 * ACTB);
    float* buf4 = (float*)(ws + 4 * ACTB);
    float* buf5 = (float*)(ws + 5 * ACTB);
    unsigned short* bufH16 = (unsigned short*)buf0;         // 32768x1024 bf16 = 67MB (buf0+buf1)
    size_t off = 6 * ACTB;
    float* bufS1 = (float*)(ws + off); off += (size_t)10240 * 256 * 4;
    float* bufS2 = (float*)(ws + off); off += (size_t)10240 * 256 * 4;
    float* bufR  = (float*)(ws + off); off += (size_t)640 * 256 * 4;
    float* bcat  = (float*)(ws + off); off += 2048 * 4;     // concat biases (8 x 256)
    unsigned short* wtbase = (unsigned short*)(ws + off);

    // transposed-weight layout (contiguous fusion groups):
    // smalls (256x256): [tq tk tv][sk sv rq][rk rv][to sq so ro] ; larges: m1w1 m1w2 m2w1 m2w2
    const int wsel[16] = {2,4,6, 12,14,18, 20,22, 8,10,16,24, 34,36,38,40};
    unsigned short* wt[16];
    { size_t o = 0;
      for (int i = 0; i < 12; i++){ wt[i] = wtbase + o; o += 65536; }
      for (int i = 12; i < 16; i++){ wt[i] = wtbase + o; o += 262144; } }
    WtArgs wa;
    for (int i = 0; i < 16; i++){ wa.w[i] = (const float*)d_in[wsel[i]]; wa.o[i] = wt[i]; }
    transp_all_k<<<7168, 256, 0, stream>>>(wa);
    BcArgs ba;                                              // tq_b tk_b tv_b | sk_b sv_b rq_b | rk_b rv_b
    { const int bs[8] = {3,5,7, 13,15,19, 21,23};
      for (int i = 0; i < 8; i++) ba.src[i] = (const float*)d_in[bs[i]];
      ba.dst = bcat; }
    bias_cat_k<<<8, 256, 0, stream>>>(ba);

    const unsigned short *G0 = wt[0], *G1 = wt[3], *G2 = wt[6];
    const unsigned short *Wto = wt[8], *Wsq = wt[9], *Wso = wt[10], *Wro = wt[11];
    const unsigned short *Wm1a = wt[12], *Wm1b = wt[13], *Wm2a = wt[14], *Wm2b = wt[15];
    const float* b_to = (const float*)d_in[9];  const float* b_sq = (const float*)d_in[11];
    const float* b_so = (const float*)d_in[17]; const float* b_ro = (const float*)d_in[25];
    const float* m1b1 = (const float*)d_in[35]; const float* m1b2 = (const float*)d_in[37];
    const float* m2b1 = (const float*)d_in[39]; const float* m2b2 = (const float*)d_in[41];

    // ---------------- stage 1 ----------------
    gemm_k<0,0,0,1><<<dim3(256,6), 256, 0, stream>>>(x, G0, bcat,
        buf0, buf1, buf2, ROWS, 768, 256);                          // q1|k1|v1
    attn64_k<<<dim3(512 * 8), 64, 0, stream>>>(buf0, buf1, buf2, buf3);
    gemm_k<0,0,0,0><<<dim3(256,2), 256, 0, stream>>>(buf3, Wto, b_to,
        buf5, nullptr, nullptr, ROWS, 256, 256);                    // o-proj
    ln_k<0><<<ROWS / 4, 256, 0, stream>>>(buf5, x, n1g, n1b, buf4); // dim_in
    gemm_k<1,0,1,0><<<dim3(256,8), 256, 0, stream>>>(buf4, Wm1a, m1b1,
        bufH16, nullptr, nullptr, ROWS, 1024, 256);                 // mlp1 hidden (gelu, bf16)
    gemm_k<0,1,0,0><<<dim3(256,2), 256, 0, stream>>>(bufH16, Wm1b, m1b2,
        buf5, nullptr, nullptr, ROWS, 256, 1024);                   // mlp1 out
    ln_k<1><<<ROWS / 4, 256, 0, stream>>>(buf5, buf4, n2g, n2b, buf0);  // dim_send (permuted)

    // ---------------- stage 2 ----------------
    gemm_k<0,0,0,0><<<dim3(5,2), 256, 0, stream>>>(router, Wsq, b_sq,
        bufR, nullptr, nullptr, 640, 256, 256);                     // router q-proj
    gemm_k<0,0,0,1><<<dim3(256,6), 256, 0, stream>>>(buf0, G1, bcat + 768,
        buf1, buf2, buf3, ROWS, 768, 256);                          // k2|v2|q3
    attn_k<10,32,1><<<dim3(1024 * 8), 256, 0, stream>>>(bufR, buf1, buf2, bufS1);
    gemm_k<0,0,0,0><<<dim3(80,2), 256, 0, stream>>>(bufS1, Wso, b_so,
        bufS2, nullptr, nullptr, 10240, 256, 256);                  // dim_buffer o-proj
    gemm_k<0,0,0,1><<<dim3(80,4), 256, 0, stream>>>(bufS2, G2, bcat + 1536,
        bufS1, buf1, nullptr, 10240, 512, 256);                     // k3|v3
    attn_k<32,10,0><<<dim3(1024 * 8), 256, 0, stream>>>(buf3, bufS1, buf1, buf2);
    gemm_k<0,0,0,0><<<dim3(256,2), 256, 0, stream>>>(buf2, Wro, b_ro,
        buf3, nullptr, nullptr, ROWS, 256, 256);                    // dim_receive o-proj
    ln_k<0><<<ROWS / 4, 256, 0, stream>>>(buf3, buf0, n3g, n3b, buf4);  // dim_enc
    gemm_k<1,0,1,0><<<dim3(256,8), 256, 0, stream>>>(buf4, Wm2a, m2b1,
        bufH16, nullptr, nullptr, ROWS, 1024, 256);                 // mlp2 hidden (gelu, bf16)
    gemm_k<0,1,0,0><<<dim3(256,2), 256, 0, stream>>>(bufH16, Wm2b, m2b2,
        buf5, nullptr, nullptr, ROWS, 256, 1024);                   // mlp2 out
    ln_k<2><<<ROWS / 4, 256, 0, stream>>>(buf5, buf4, n4g, n4b, (float*)d_out);
}

// Round 8
// 524.943 us; speedup vs baseline: 1.6159x; 1.1766x over previous
//
#include <hip/hip_runtime.h>
#include <hip/hip_bf16.h>

#define DIM   256
#define NH    8
#define HE    32
#define ROWS  32768          // B*TS_D*SEG = 16*32*64
#define EPS_LN 1e-3f

typedef float f32x4 __attribute__((ext_vector_type(4)));
typedef short s16x8 __attribute__((ext_vector_type(8)));
typedef short s16x4 __attribute__((ext_vector_type(4)));
typedef __bf16 bf16x8 __attribute__((ext_vector_type(8)));

__device__ __forceinline__ unsigned short f2bf(float f){
    union { float f; unsigned int u; } v; v.f = f;
    unsigned int u = v.u;
    return (unsigned short)((u + 0x7fffu + ((u >> 16) & 1u)) >> 16);   // RNE
}
__device__ __forceinline__ float bf2f(unsigned short u){
    union { unsigned int i; float f; } v; v.i = (unsigned int)u << 16; return v.f;
}
__device__ __forceinline__ float gelu_f(float x){
    return 0.5f * x * (1.0f + erff(x * 0.70710678118654752440f));      // exact gelu
}
// builtin MFMA only (asm MFMA caused R2/R3/R5 NaNs: no hazard waits in INLINEASM)
__device__ __forceinline__ void mfma16i(f32x4& acc, s16x8 a, s16x8 b){
    acc = __builtin_amdgcn_mfma_f32_16x16x32_bf16(
        __builtin_bit_cast(bf16x8, a), __builtin_bit_cast(bf16x8, b), acc, 0, 0, 0);
}
// async global->LDS, 16B/lane; LDS dest = wave-uniform base + lane*16
__device__ __forceinline__ void gld16(const unsigned short* g, unsigned short* l){
    __builtin_amdgcn_global_load_lds(
        (const __attribute__((address_space(1))) unsigned int*)g,
        (__attribute__((address_space(3))) unsigned int*)l, 16, 0, 0);
}

// ---------------- fp32 -> bf16 convert (x, router) --------------------------
__global__ __launch_bounds__(256) void conv_k(const float* __restrict__ in,
        unsigned short* __restrict__ out, int n8){
    int idx = blockIdx.x * 256 + threadIdx.x;
    if (idx >= n8) return;
    const float4 a = *(const float4*)(in + idx * 8);
    const float4 b = *(const float4*)(in + idx * 8 + 4);
    s16x8 v;
    v[0]=(short)f2bf(a.x); v[1]=(short)f2bf(a.y); v[2]=(short)f2bf(a.z); v[3]=(short)f2bf(a.w);
    v[4]=(short)f2bf(b.x); v[5]=(short)f2bf(b.y); v[6]=(short)f2bf(b.z); v[7]=(short)f2bf(b.w);
    *(s16x8*)(out + idx * 8) = v;
}

// ---------------- fused weight transpose + bf16 convert (all 16 weights) ----
struct WtArgs { const float* w[16]; unsigned short* o[16]; };
__global__ __launch_bounds__(256) void transp_all_k(WtArgs a){
    int idx = blockIdx.x * 256 + threadIdx.x;          // 0 .. 1835007
    int wi, rem, K, N;
    if (idx < 786432){ wi = idx >> 16; rem = idx & 65535; K = 256; N = 256; }
    else { int t = idx - 786432; wi = 12 + (t >> 18); rem = t & 262143;
           if ((wi & 1) == 0){ K = 256; N = 1024; } else { K = 1024; N = 256; } }
    int ln = (N == 256) ? 8 : 10;
    int k = rem >> ln, n = rem & (N - 1);
    a.o[wi][n * K + k] = f2bf(a.w[wi][rem]);
}

// ---------------- concat biases for fused GEMM groups -----------------------
struct BcArgs { const float* src[8]; float* dst; };
__global__ __launch_bounds__(256) void bias_cat_k(BcArgs a){
    int idx = blockIdx.x * 256 + threadIdx.x;          // 0..2047
    a.dst[idx] = a.src[idx >> 8][idx & 255];
}

// ---------------- GEMM: C = act(A @ W + bias), all-bf16, counted-vmcnt ------
// A bf16 MxK, Wt bf16 NxK. 128x128 tile, BK=32, double-buffered LDS, both
// operands via global_load_lds with XOR-swizzled source (chunk = j ^ ((row>>1)&3)),
// ds_read applies the same swizzle. Pipeline: stage(next) -> vmcnt(4) ->
// barrier -> ds_read+MFMA -> barrier (next-tile loads stay in flight).
template<int ACT, int SPLIT>
__global__ __launch_bounds__(256) void gemm_k(const unsigned short* __restrict__ A,
        const unsigned short* __restrict__ Wt, const float* __restrict__ bias,
        unsigned short* C0, unsigned short* C1, unsigned short* C2,
        int M, int N, int K){
    __shared__ __align__(16) unsigned short As[2][128 * 32];   // linear rows of 64B
    __shared__ __align__(16) unsigned short Bs[2][128 * 32];
    const int tid  = threadIdx.x;
    const long row0 = (long)blockIdx.x * 128;
    const long col0 = (long)blockIdx.y * 128;
    const int w = tid >> 6, lane = tid & 63;
    const int wm = w >> 1, wn = w & 1;
    const int l15 = lane & 15, g = lane >> 4;
    // staging: wave w covers tile rows [32w,32w+32); lane -> row 32w+(lane>>2),
    // physical chunk lane&3 holds logical chunk (lane&3)^((lane>>3)&3)
    const int jsrc = ((lane & 3) ^ ((lane >> 3) & 3)) * 8;
    const unsigned short* Ag = A  + (size_t)(row0 + 32 * w + (lane >> 2)) * K + jsrc;
    const unsigned short* Bg = Wt + (size_t)(col0 + 32 * w + (lane >> 2)) * K + jsrc;
    unsigned short* Al0[2] = { &As[0][(32 * w) * 32], &As[1][(32 * w) * 32] };
    unsigned short* Bl0[2] = { &Bs[0][(32 * w) * 32], &Bs[1][(32 * w) * 32] };

    f32x4 acc[4][4];
    #pragma unroll
    for (int i = 0; i < 4; i++)
        #pragma unroll
        for (int jj = 0; jj < 4; jj++) acc[i][jj] = (f32x4){0,0,0,0};

    const int NT = K >> 5;
    // prologue: stage tile 0 into buffer 0
    gld16(Ag, Al0[0]);          gld16(Ag + 16 * K, Al0[0] + 16 * 32);
    gld16(Bg, Bl0[0]);          gld16(Bg + 16 * K, Bl0[0] + 16 * 32);
    for (int t = 0; t < NT; ++t){
        const int cur = t & 1;
        if (t + 1 < NT){
            const int kk = (t + 1) << 5;
            gld16(Ag + kk, Al0[cur ^ 1]);  gld16(Ag + kk + 16 * K, Al0[cur ^ 1] + 16 * 32);
            gld16(Bg + kk, Bl0[cur ^ 1]);  gld16(Bg + kk + 16 * K, Bl0[cur ^ 1] + 16 * 32);
            asm volatile("s_waitcnt vmcnt(4)" ::: "memory");   // cur tile complete
        } else {
            asm volatile("s_waitcnt vmcnt(0)" ::: "memory");
        }
        __builtin_amdgcn_sched_barrier(0);
        __builtin_amdgcn_s_barrier();
        __builtin_amdgcn_sched_barrier(0);
        s16x8 af[4], bf[4];
        #pragma unroll
        for (int mi = 0; mi < 4; mi++){
            const int r = mi * 16 + l15;
            af[mi] = *(const s16x8*)&As[cur][(wm * 64 + r) * 32 + ((g ^ ((l15 >> 1) & 3)) * 8)];
        }
        #pragma unroll
        for (int ni = 0; ni < 4; ni++){
            const int r = ni * 16 + l15;
            bf[ni] = *(const s16x8*)&Bs[cur][(wn * 64 + r) * 32 + ((g ^ ((l15 >> 1) & 3)) * 8)];
        }
        #pragma unroll
        for (int mi = 0; mi < 4; mi++)
            #pragma unroll
            for (int ni = 0; ni < 4; ni++)
                mfma16i(acc[mi][ni], af[mi], bf[ni]);
        __builtin_amdgcn_sched_barrier(0);
        __builtin_amdgcn_s_barrier();
    }
    // epilogue
    const int sel = SPLIT ? (int)(col0 >> 8) : 0;
    unsigned short* Cp = SPLIT ? (sel == 0 ? C0 : (sel == 1 ? C1 : C2)) : C0;
    const int ldc = SPLIT ? 256 : N;
    float bb[4];
    #pragma unroll
    for (int ni = 0; ni < 4; ni++) bb[ni] = bias[col0 + wn * 64 + ni * 16 + l15];
    #pragma unroll
    for (int mi = 0; mi < 4; mi++){
        const long grow = row0 + wm * 64 + mi * 16 + g * 4;
        #pragma unroll
        for (int ni = 0; ni < 4; ni++){
            int gcol = (int)col0 + wn * 64 + ni * 16 + l15;
            int lcol = SPLIT ? (gcol & 255) : gcol;
            #pragma unroll
            for (int r = 0; r < 4; r++){
                float v = acc[mi][ni][r] + bb[ni];
                if (ACT) v = gelu_f(v);
                Cp[(grow + r) * ldc + lcol] = f2bf(v);
            }
        }
    }
}

// ---------------- MFMA attention, L=S=64, bf16 I/O: 1 wave/(j,h) ------------
__global__ __launch_bounds__(64) void attn64_k(const unsigned short* __restrict__ Q,
        const unsigned short* __restrict__ Kp, const unsigned short* __restrict__ Vp,
        unsigned short* __restrict__ O){
    __shared__ __align__(16) unsigned short P[64][72];     // P[q][s] bf16
    const int j = blockIdx.x >> 3, h = blockIdx.x & 7;
    const int lane = threadIdx.x;
    const int l15 = lane & 15, g = lane >> 4;
    const long base = (long)j * 64 * DIM;
    const int hoff = h * HE;
    const float scale = 0.17677669529663687f;   // 1/sqrt(32)
    s16x8 kf[4], qf[4];
    #pragma unroll
    for (int b = 0; b < 4; b++){
        kf[b] = *(const s16x8*)(Kp + base + (long)(b * 16 + l15) * DIM + hoff + g * 8);
        qf[b] = *(const s16x8*)(Q  + base + (long)(b * 16 + l15) * DIM + hoff + g * 8);
    }
    f32x4 st[4][4];
    #pragma unroll
    for (int sb = 0; sb < 4; sb++)
        #pragma unroll
        for (int qb = 0; qb < 4; qb++) st[sb][qb] = (f32x4){0,0,0,0};
    #pragma unroll
    for (int sb = 0; sb < 4; sb++)
        #pragma unroll
        for (int qb = 0; qb < 4; qb++) mfma16i(st[sb][qb], kf[sb], qf[qb]);
    #pragma unroll
    for (int sb = 0; sb < 4; sb++)
        #pragma unroll
        for (int qb = 0; qb < 4; qb++)
            #pragma unroll
            for (int r = 0; r < 4; r++) st[sb][qb][r] *= scale;
    #pragma unroll
    for (int qb = 0; qb < 4; qb++){
        float mx = -1e30f;
        #pragma unroll
        for (int sb = 0; sb < 4; sb++)
            #pragma unroll
            for (int r = 0; r < 4; r++) mx = fmaxf(mx, st[sb][qb][r]);
        mx = fmaxf(mx, __shfl_xor(mx, 16, 64));
        mx = fmaxf(mx, __shfl_xor(mx, 32, 64));
        float sum = 0.f;
        #pragma unroll
        for (int sb = 0; sb < 4; sb++)
            #pragma unroll
            for (int r = 0; r < 4; r++){
                float e = expf(st[sb][qb][r] - mx);
                st[sb][qb][r] = e; sum += e;
            }
        sum += __shfl_xor(sum, 16, 64);
        sum += __shfl_xor(sum, 32, 64);
        float inv = 1.f / sum;
        const int q = qb * 16 + l15;
        #pragma unroll
        for (int sb = 0; sb < 4; sb++){
            s16x4 p4;
            #pragma unroll
            for (int r = 0; r < 4; r++) p4[r] = (short)f2bf(st[sb][qb][r] * inv);
            *(s16x4*)&P[q][sb * 16 + g * 4] = p4;
        }
    }
    __syncthreads();
    f32x4 o[4][2];
    #pragma unroll
    for (int qb = 0; qb < 4; qb++)
        #pragma unroll
        for (int eb = 0; eb < 2; eb++) o[qb][eb] = (f32x4){0,0,0,0};
    #pragma unroll
    for (int ksl = 0; ksl < 2; ksl++){
        s16x8 pf[4], vf[2];
        #pragma unroll
        for (int qb = 0; qb < 4; qb++)
            pf[qb] = *(const s16x8*)&P[qb * 16 + l15][ksl * 32 + g * 8];
        #pragma unroll
        for (int eb = 0; eb < 2; eb++){
            const unsigned short* vp = Vp + base + (long)(ksl * 32 + g * 8) * DIM + hoff + eb * 16 + l15;
            s16x8 vv;
            #pragma unroll
            for (int jj = 0; jj < 8; jj++) vv[jj] = (short)vp[(long)jj * DIM];
            vf[eb] = vv;
        }
        #pragma unroll
        for (int qb = 0; qb < 4; qb++)
            #pragma unroll
            for (int eb = 0; eb < 2; eb++) mfma16i(o[qb][eb], pf[qb], vf[eb]);
    }
    #pragma unroll
    for (int qb = 0; qb < 4; qb++)
        #pragma unroll
        for (int eb = 0; eb < 2; eb++){
            const int q = qb * 16 + g * 4;
            unsigned short* op = O + base + (long)q * DIM + hoff + eb * 16 + l15;
            #pragma unroll
            for (int r = 0; r < 4; r++) op[(long)r * DIM] = f2bf(o[qb][eb][r]);
        }
}

// ---------------- fused attention (small shapes), bf16 I/O, VALU ------------
template<int L, int S, int QMODE>
__global__ __launch_bounds__(256) void attn_k(const unsigned short* __restrict__ Q,
        const unsigned short* __restrict__ Kp, const unsigned short* __restrict__ Vp,
        unsigned short* __restrict__ O){
    __shared__ float Qs[L][36];
    __shared__ float Ks[S][36];
    __shared__ float Vs[S][36];
    __shared__ float Sc[L][S + 1];
    const int j = blockIdx.x >> 3, h = blockIdx.x & 7;
    const int tid = threadIdx.x;
    const long qbase = QMODE ? (long)(j >> 4) * L : (long)j * L;
    const long kbase = (long)j * S;
    const long obase = (long)j * L;
    const int hoff = h * HE;
    for (int idx = tid; idx < L * 4; idx += 256){
        int i = idx >> 2, e8 = (idx & 3) * 8;
        s16x8 v = *(const s16x8*)(Q + (qbase + i) * DIM + hoff + e8);
        #pragma unroll
        for (int t = 0; t < 8; t++) Qs[i][e8 + t] = bf2f((unsigned short)v[t]);
    }
    for (int idx = tid; idx < S * 4; idx += 256){
        int i = idx >> 2, e8 = (idx & 3) * 8;
        s16x8 vk = *(const s16x8*)(Kp + (kbase + i) * DIM + hoff + e8);
        s16x8 vv = *(const s16x8*)(Vp + (kbase + i) * DIM + hoff + e8);
        #pragma unroll
        for (int t = 0; t < 8; t++){
            Ks[i][e8 + t] = bf2f((unsigned short)vk[t]);
            Vs[i][e8 + t] = bf2f((unsigned short)vv[t]);
        }
    }
    __syncthreads();
    for (int idx = tid; idx < L * S; idx += 256){
        int i = idx / S, jj = idx % S;
        float d = 0.f;
        #pragma unroll
        for (int q4 = 0; q4 < 8; q4++){
            float4 a = *reinterpret_cast<const float4*>(&Qs[i][q4 * 4]);
            float4 b = *reinterpret_cast<const float4*>(&Ks[jj][q4 * 4]);
            d += a.x * b.x + a.y * b.y + a.z * b.z + a.w * b.w;
        }
        Sc[i][jj] = d * 0.17677669529663687f;
    }
    __syncthreads();
    if (tid < L){
        float mx = -1e30f;
        for (int jj = 0; jj < S; jj++) mx = fmaxf(mx, Sc[tid][jj]);
        float s = 0.f;
        for (int jj = 0; jj < S; jj++){ float e = expf(Sc[tid][jj] - mx); Sc[tid][jj] = e; s += e; }
        float inv = 1.f / s;
        for (int jj = 0; jj < S; jj++) Sc[tid][jj] *= inv;
    }
    __syncthreads();
    for (int idx = tid; idx < L * 8; idx += 256){
        int i = idx >> 3, e4 = (idx & 7) << 2;
        float4 o = {0.f, 0.f, 0.f, 0.f};
        for (int jj = 0; jj < S; jj++){
            float s = Sc[i][jj];
            float4 v = *reinterpret_cast<const float4*>(&Vs[jj][e4]);
            o.x += s * v.x; o.y += s * v.y; o.z += s * v.z; o.w += s * v.w;
        }
        s16x4 p;
        p[0] = (short)f2bf(o.x); p[1] = (short)f2bf(o.y);
        p[2] = (short)f2bf(o.z); p[3] = (short)f2bf(o.w);
        *(s16x4*)(O + (obase + i) * DIM + hoff + e4) = p;
    }
}

// ---------------- LayerNorm of (X + R), bf16 in, bf16/fp32 out --------------
template<int PERM, int OUTF32>
__global__ __launch_bounds__(256) void ln_k(const unsigned short* __restrict__ X,
        const unsigned short* __restrict__ R, const float* __restrict__ g,
        const float* __restrict__ be, void* __restrict__ Y){
    const int wid = threadIdx.x >> 6, lane = threadIdx.x & 63;
    const long row = (long)blockIdx.x * 4 + wid;
    s16x4 xv4 = *(const s16x4*)(X + row * DIM + lane * 4);
    s16x4 rv4 = *(const s16x4*)(R + row * DIM + lane * 4);
    float4 v = { bf2f((unsigned short)xv4[0]) + bf2f((unsigned short)rv4[0]),
                 bf2f((unsigned short)xv4[1]) + bf2f((unsigned short)rv4[1]),
                 bf2f((unsigned short)xv4[2]) + bf2f((unsigned short)rv4[2]),
                 bf2f((unsigned short)xv4[3]) + bf2f((unsigned short)rv4[3]) };
    float s = v.x + v.y + v.z + v.w;
    #pragma unroll
    for (int m = 1; m < 64; m <<= 1) s += __shfl_xor(s, m, 64);
    float mean = s * (1.f / 256.f);
    float dx = v.x - mean, dy = v.y - mean, dz = v.z - mean, dw = v.w - mean;
    float q = dx * dx + dy * dy + dz * dz + dw * dw;
    #pragma unroll
    for (int m = 1; m < 64; m <<= 1) q += __shfl_xor(q, m, 64);
    float rstd = rsqrtf(q * (1.f / 256.f) + EPS_LN);
    float4 gv = *reinterpret_cast<const float4*>(g  + lane * 4);
    float4 bv = *reinterpret_cast<const float4*>(be + lane * 4);
    long rout = row;
    if (PERM == 1){ int b = (int)(row >> 11), rem = (int)row & 2047, t = rem >> 6, sg = rem & 63;
                    rout = (long)b * 2048 + sg * 32 + t; }
    if (PERM == 2){ int b = (int)(row >> 11), rem = (int)row & 2047, sg = rem >> 5, t = rem & 31;
                    rout = (long)b * 2048 + t * 64 + sg; }
    float4 o = { dx * rstd * gv.x + bv.x, dy * rstd * gv.y + bv.y,
                 dz * rstd * gv.z + bv.z, dw * rstd * gv.w + bv.w };
    if (OUTF32){
        *reinterpret_cast<float4*>((float*)Y + rout * DIM + lane * 4) = o;
    } else {
        s16x4 p;
        p[0] = (short)f2bf(o.x); p[1] = (short)f2bf(o.y);
        p[2] = (short)f2bf(o.z); p[3] = (short)f2bf(o.w);
        *(s16x4*)((unsigned short*)Y + rout * DIM + lane * 4) = p;
    }
}

extern "C" void kernel_launch(void* const* d_in, const int* in_sizes, int n_in,
                              void* d_out, int out_size, void* d_ws, size_t ws_size,
                              hipStream_t stream){
    const float* x      = (const float*)d_in[0];
    const float* router = (const float*)d_in[1];
    const float* n1g = (const float*)d_in[26]; const float* n1b = (const float*)d_in[27];
    const float* n2g = (const float*)d_in[28]; const float* n2b = (const float*)d_in[29];
    const float* n3g = (const float*)d_in[30]; const float* n3b = (const float*)d_in[31];
    const float* n4g = (const float*)d_in[32]; const float* n4b = (const float*)d_in[33];

    char* ws = (char*)d_ws;
    const size_t ACT2 = (size_t)ROWS * DIM * 2;            // 16.78 MB (bf16)
    unsigned short* x16  = (unsigned short*)(ws);
    unsigned short* buf0 = (unsigned short*)(ws + 1 * ACT2);
    unsigned short* buf1 = (unsigned short*)(ws + 2 * ACT2);
    unsigned short* buf2 = (unsigned short*)(ws + 3 * ACT2);
    unsigned short* buf3 = (unsigned short*)(ws + 4 * ACT2);
    unsigned short* buf4 = (unsigned short*)(ws + 5 * ACT2);
    unsigned short* buf5 = (unsigned short*)(ws + 6 * ACT2);
    size_t off = 7 * ACT2;
    unsigned short* bufH = (unsigned short*)(ws + off); off += (size_t)ROWS * 1024 * 2;
    unsigned short* bufS1 = (unsigned short*)(ws + off); off += (size_t)10240 * 256 * 2;
    unsigned short* bufS2 = (unsigned short*)(ws + off); off += (size_t)10240 * 256 * 2;
    unsigned short* r16   = (unsigned short*)(ws + off); off += (size_t)640 * 256 * 2;
    unsigned short* bufRt = (unsigned short*)(ws + off); off += (size_t)640 * 256 * 2;
    float* bcat = (float*)(ws + off); off += 2048 * 4;
    unsigned short* wtbase = (unsigned short*)(ws + off);

    // transposed-weight layout (contiguous fusion groups):
    // smalls (256x256): [tq tk tv][sk sv rq][rk rv][to sq so ro] ; larges: m1w1 m1w2 m2w1 m2w2
    const int wsel[16] = {2,4,6, 12,14,18, 20,22, 8,10,16,24, 34,36,38,40};
    unsigned short* wt[16];
    { size_t o = 0;
      for (int i = 0; i < 12; i++){ wt[i] = wtbase + o; o += 65536; }
      for (int i = 12; i < 16; i++){ wt[i] = wtbase + o; o += 262144; } }
    WtArgs wa;
    for (int i = 0; i < 16; i++){ wa.w[i] = (const float*)d_in[wsel[i]]; wa.o[i] = wt[i]; }
    transp_all_k<<<7168, 256, 0, stream>>>(wa);
    BcArgs ba;                                              // tq_b tk_b tv_b | sk_b sv_b rq_b | rk_b rv_b
    { const int bs[8] = {3,5,7, 13,15,19, 21,23};
      for (int i = 0; i < 8; i++) ba.src[i] = (const float*)d_in[bs[i]];
      ba.dst = bcat; }
    bias_cat_k<<<8, 256, 0, stream>>>(ba);
    conv_k<<<(ROWS * DIM / 8 + 255) / 256, 256, 0, stream>>>(x, x16, ROWS * DIM / 8);
    conv_k<<<(640 * 256 / 8 + 255) / 256, 256, 0, stream>>>(router, r16, 640 * 256 / 8);

    const unsigned short *G0 = wt[0], *G1 = wt[3], *G2 = wt[6];
    const unsigned short *Wto = wt[8], *Wsq = wt[9], *Wso = wt[10], *Wro = wt[11];
    const unsigned short *Wm1a = wt[12], *Wm1b = wt[13], *Wm2a = wt[14], *Wm2b = wt[15];
    const float* b_to = (const float*)d_in[9];  const float* b_sq = (const float*)d_in[11];
    const float* b_so = (const float*)d_in[17]; const float* b_ro = (const float*)d_in[25];
    const float* m1b1 = (const float*)d_in[35]; const float* m1b2 = (const float*)d_in[37];
    const float* m2b1 = (const float*)d_in[39]; const float* m2b2 = (const float*)d_in[41];

    // ---------------- stage 1 ----------------
    gemm_k<0,1><<<dim3(256,6), 256, 0, stream>>>(x16, G0, bcat,
        buf0, buf1, buf2, ROWS, 768, 256);                          // q1|k1|v1
    attn64_k<<<dim3(512 * 8), 64, 0, stream>>>(buf0, buf1, buf2, buf3);
    gemm_k<0,0><<<dim3(256,2), 256, 0, stream>>>(buf3, Wto, b_to,
        buf5, nullptr, nullptr, ROWS, 256, 256);                    // o-proj
    ln_k<0,0><<<ROWS / 4, 256, 0, stream>>>(buf5, x16, n1g, n1b, buf4);  // dim_in
    gemm_k<1,0><<<dim3(256,8), 256, 0, stream>>>(buf4, Wm1a, m1b1,
        bufH, nullptr, nullptr, ROWS, 1024, 256);                   // mlp1 hidden (gelu)
    gemm_k<0,0><<<dim3(256,2), 256, 0, stream>>>(bufH, Wm1b, m1b2,
        buf5, nullptr, nullptr, ROWS, 256, 1024);                   // mlp1 out
    ln_k<1,0><<<ROWS / 4, 256, 0, stream>>>(buf5, buf4, n2g, n2b, buf0); // dim_send (permuted)

    // ---------------- stage 2 ----------------
    gemm_k<0,0><<<dim3(5,2), 256, 0, stream>>>(r16, Wsq, b_sq,
        bufRt, nullptr, nullptr, 640, 256, 256);                    // router q-proj
    gemm_k<0,1><<<dim3(256,6), 256, 0, stream>>>(buf0, G1, bcat + 768,
        buf1, buf2, buf3, ROWS, 768, 256);                          // k2|v2|q3
    attn_k<10,32,1><<<dim3(1024 * 8), 256, 0, stream>>>(bufRt, buf1, buf2, bufS1);
    gemm_k<0,0><<<dim3(80,2), 256, 0, stream>>>(bufS1, Wso, b_so,
        bufS2, nullptr, nullptr, 10240, 256, 256);                  // dim_buffer o-proj
    gemm_k<0,1><<<dim3(80,4), 256, 0, stream>>>(bufS2, G2, bcat + 1536,
        bufS1, buf1, nullptr, 10240, 512, 256);                     // k3|v3
    attn_k<32,10,0><<<dim3(1024 * 8), 256, 0, stream>>>(buf3, bufS1, buf1, buf2);
    gemm_k<0,0><<<dim3(256,2), 256, 0, stream>>>(buf2, Wro, b_ro,
        buf3, nullptr, nullptr, ROWS, 256, 256);                    // dim_receive o-proj
    ln_k<0,0><<<ROWS / 4, 256, 0, stream>>>(buf3, buf0, n3g, n3b, buf4); // dim_enc
    gemm_k<1,0><<<dim3(256,8), 256, 0, stream>>>(buf4, Wm2a, m2b1,
        bufH, nullptr, nullptr, ROWS, 1024, 256);                   // mlp2 hidden (gelu)
    gemm_k<0,0><<<dim3(256,2), 256, 0, stream>>>(bufH, Wm2b, m2b2,
        buf5, nullptr, nullptr, ROWS, 256, 1024);                   // mlp2 out
    ln_k<2,1><<<ROWS / 4, 256, 0, stream>>>(buf5, buf4, n4g, n4b, (float*)d_out);
}